// Round 1
// baseline (325.699 us; speedup 1.0000x reference)
//
#include <hip/hip_runtime.h>

typedef __bf16 bf16x8 __attribute__((ext_vector_type(8)));
typedef float f32x4 __attribute__((ext_vector_type(4)));

#define AS1 __attribute__((address_space(1)))
#define AS3 __attribute__((address_space(3)))

__device__ __forceinline__ void gload_lds16(const void* g, void* l) {
  __builtin_amdgcn_global_load_lds((const AS1 void*)g, (AS3 void*)l, 16, 0, 0);
}

// ---------------------------------------------------------------- fp32 -> bf16
__global__ __launch_bounds__(256) void cvt_f32_bf16(const float* __restrict__ in,
                                                    __bf16* __restrict__ o, int n8) {
  int i = blockIdx.x * 256 + threadIdx.x;
  if (i >= n8) return;
  const float4* p = (const float4*)in;
  float4 a = p[2 * i], b = p[2 * i + 1];
  bf16x8 v;
  v[0] = (__bf16)a.x; v[1] = (__bf16)a.y; v[2] = (__bf16)a.z; v[3] = (__bf16)a.w;
  v[4] = (__bf16)b.x; v[5] = (__bf16)b.y; v[6] = (__bf16)b.z; v[7] = (__bf16)b.w;
  *(bf16x8*)(o + (size_t)i * 8) = v;
}

// ---------------------------------------------------------------- GEMM (B^T)
// C[M,N] = A[M,K] @ B[N,K]^T  (+bias[n]); m97-style 128x128 tile, BK=32.
// OM==0: bf16 output.  OM==1: fp32 output with sigmoid.  NG: guard N (B rows clamped).
template <int OM, bool NG>
__global__ __launch_bounds__(256)
void gemm_bt(const __bf16* __restrict__ A, const __bf16* __restrict__ B,
             const float* __restrict__ bias, void* __restrict__ Cout,
             int N, int K, int tiles_m) {
  __shared__ __bf16 sA[128 * 32];
  __shared__ __bf16 sB[128 * 32];
  const int bx = blockIdx.x;
  const int tm = bx % tiles_m, tn = bx / tiles_m;
  const int t = threadIdx.x;
  const int lane = t & 63;
  const int w = t >> 6, wm = w >> 1, wn = w & 1;

  f32x4 acc[4][4];
#pragma unroll
  for (int m = 0; m < 4; ++m)
#pragma unroll
    for (int n = 0; n < 4; ++n) acc[m][n] = (f32x4){0.f, 0.f, 0.f, 0.f};

  for (int k0 = 0; k0 < K; k0 += 32) {
#pragma unroll
    for (int s = 0; s < 2; ++s) {
      const int i = t + s * 256;
      const int row = i >> 2, cb = i & 3;
      gload_lds16(A + (size_t)(tm * 128 + row) * K + k0 + cb * 8, sA + i * 8);
      int brow = tn * 128 + row;
      if (NG) brow = brow < N ? brow : N - 1;
      gload_lds16(B + (size_t)brow * K + k0 + cb * 8, sB + i * 8);
    }
    __syncthreads();
    bf16x8 af[4], bfr[4];
#pragma unroll
    for (int m = 0; m < 4; ++m)
      af[m] = *(const bf16x8*)(sA + (wm * 64 + m * 16 + (lane & 15)) * 32 + (lane >> 4) * 8);
#pragma unroll
    for (int n = 0; n < 4; ++n)
      bfr[n] = *(const bf16x8*)(sB + (wn * 64 + n * 16 + (lane & 15)) * 32 + (lane >> 4) * 8);
#pragma unroll
    for (int m = 0; m < 4; ++m)
#pragma unroll
      for (int n = 0; n < 4; ++n)
        acc[m][n] = __builtin_amdgcn_mfma_f32_16x16x32_bf16(af[m], bfr[n], acc[m][n], 0, 0, 0);
    __syncthreads();
  }

#pragma unroll
  for (int n = 0; n < 4; ++n) {
    const int col = tn * 128 + wn * 64 + n * 16 + (lane & 15);
    const bool ok = (!NG) || (col < N);
    const float bv = ok ? bias[col] : 0.f;
#pragma unroll
    for (int m = 0; m < 4; ++m) {
#pragma unroll
      for (int j = 0; j < 4; ++j) {
        if (!ok) continue;
        const int row = tm * 128 + wm * 64 + m * 16 + (lane >> 4) * 4 + j;
        const float v = acc[m][n][j] + bv;
        if (OM == 0)
          ((__bf16*)Cout)[(size_t)row * N + col] = (__bf16)v;
        else
          ((float*)Cout)[(size_t)row * N + col] = 1.f / (1.f + __expf(-v));
      }
    }
  }
}

// ---------------------------------------------------------------- attention
// One block per batch b. Phase1: S = Q_b K_b^T via MFMA (K-chunked LDS staging).
// Phase2: softmax(S*mask/sqrt(D)) rows (threads 0..79). Phase3: context = P @ F
// via MFMA (P, F^T re-staged bf16 in LDS), fused epilogue.
__global__ __launch_bounds__(256)
void attn_kernel(const __bf16* __restrict__ Qb, const __bf16* __restrict__ Kb,
                 const float* __restrict__ feats, const float* __restrict__ mask,
                 const float* __restrict__ adj, float* __restrict__ out) {
  __shared__ char smem[107520];
  __bf16* sQ = (__bf16*)smem;                  // [80][256] bf16 (phase 1)
  __bf16* sK = (__bf16*)(smem + 40960);        // [80][256] bf16 (phase 1)
  float* S   = (float*)(smem + 81920);         // [80][80] fp32
  __bf16* Ft = (__bf16*)smem;                  // [208][96] bf16 (phase 3)
  __bf16* P  = (__bf16*)(smem + 40960);        // [80][96] bf16 (phase 3)

  const int b = blockIdx.x;
  const int t = threadIdx.x;
  const int lane = t & 63;
  const int w = t >> 6;

  const __bf16* Qbase = Qb + (size_t)b * 80 * 2048;
  const __bf16* Kbase = Kb + (size_t)b * 80 * 2048;

  // ---- Phase 1: S = Q K^T
  f32x4 acc[7];
#pragma unroll
  for (int u = 0; u < 7; ++u) acc[u] = (f32x4){0.f, 0.f, 0.f, 0.f};

  for (int kc = 0; kc < 2048; kc += 256) {
#pragma unroll
    for (int s = 0; s < 10; ++s) {
      const int i = t + s * 256;
      const int row = i >> 5, cb = i & 31;
      gload_lds16(Qbase + (size_t)row * 2048 + kc + cb * 8, sQ + i * 8);
    }
#pragma unroll
    for (int s = 0; s < 10; ++s) {
      const int i = t + s * 256;
      const int row = i >> 5, cb = i & 31;
      gload_lds16(Kbase + (size_t)row * 2048 + kc + cb * 8, sK + i * 8);
    }
    __syncthreads();
#pragma unroll
    for (int u = 0; u < 7; ++u) {
      const int tl = w + u * 4;
      if (tl < 25) {
        const int qi = tl / 5, kj = tl % 5;
#pragma unroll
        for (int k0 = 0; k0 < 256; k0 += 32) {
          bf16x8 a = *(const bf16x8*)(sQ + (qi * 16 + (lane & 15)) * 256 + k0 + (lane >> 4) * 8);
          bf16x8 kk = *(const bf16x8*)(sK + (kj * 16 + (lane & 15)) * 256 + k0 + (lane >> 4) * 8);
          acc[u] = __builtin_amdgcn_mfma_f32_16x16x32_bf16(a, kk, acc[u], 0, 0, 0);
        }
      }
    }
    __syncthreads();
  }
  // write S
#pragma unroll
  for (int u = 0; u < 7; ++u) {
    const int tl = w + u * 4;
    if (tl < 25) {
      const int qi = tl / 5, kj = tl % 5;
#pragma unroll
      for (int j = 0; j < 4; ++j) {
        const int r = qi * 16 + (lane >> 4) * 4 + j;
        const int c = kj * 16 + (lane & 15);
        S[r * 80 + c] = acc[u][j];
      }
    }
  }
  __syncthreads();

  // ---- Phase 2: softmax rows (threads 0..79) + stage F^T bf16 (all threads)
  if (t < 80) {
    const float scale = 0.02209708691207961f;  // 1/sqrt(2048)
    float mx = -1e30f;
    for (int k = 0; k < 80; ++k) {
      float v = S[t * 80 + k] * scale * mask[t * 80 + k];
      S[t * 80 + k] = v;
      mx = fmaxf(mx, v);
    }
    float sum = 0.f;
    for (int k = 0; k < 80; ++k) {
      float e = __expf(S[t * 80 + k] - mx);
      S[t * 80 + k] = e;
      sum += e;
    }
    const float r = 1.f / sum;
    for (int k = 0; k < 80; ++k) P[t * 96 + k] = (__bf16)(S[t * 80 + k] * r);
    for (int k = 80; k < 96; ++k) P[t * 96 + k] = (__bf16)0.f;  // zero K-pad
  }
  // stage F^T: Ft[h][k] = feats[b][k][h]  (k<80; pad cols k>=80 are killed by P==0)
  for (int idx = t; idx < 15680; idx += 256) {
    const int k = idx / 196, h = idx - k * 196;
    Ft[h * 96 + k] = (__bf16)feats[(size_t)b * 15680 + idx];
  }
  __syncthreads();

  // ---- Phase 3: context = P @ F, fused epilogue
  for (int u = 0; u < 17; ++u) {
    const int tl = w + u * 4;
    if (tl >= 65) break;
    const int ci = tl / 13, hj = tl - ci * 13;
    f32x4 a2 = (f32x4){0.f, 0.f, 0.f, 0.f};
#pragma unroll
    for (int k0 = 0; k0 < 96; k0 += 32) {
      bf16x8 pa = *(const bf16x8*)(P + (ci * 16 + (lane & 15)) * 96 + k0 + (lane >> 4) * 8);
      bf16x8 fb = *(const bf16x8*)(Ft + (hj * 16 + (lane & 15)) * 96 + k0 + (lane >> 4) * 8);
      a2 = __builtin_amdgcn_mfma_f32_16x16x32_bf16(pa, fb, a2, 0, 0, 0);
    }
#pragma unroll
    for (int j = 0; j < 4; ++j) {
      const int c = ci * 16 + (lane >> 4) * 4 + j;
      const int h = hj * 16 + (lane & 15);
      if (h < 196) {
        const size_t o = (size_t)b * 15680 + (size_t)c * 196 + h;
        out[o] = (feats[o] + a2[j]) * adj[o];
      }
    }
  }
}

// ---------------------------------------------------------------- launch
extern "C" void kernel_launch(void* const* d_in, const int* in_sizes, int n_in,
                              void* d_out, int out_size, void* d_ws, size_t ws_size,
                              hipStream_t stream) {
  const float* features = (const float*)d_in[0];  // [64,80,14,14]
  const float* sem      = (const float*)d_in[1];  // [64,80,2048]
  const float* mask     = (const float*)d_in[2];  // [80,80]
  const float* Wq_w     = (const float*)d_in[3];  // [2048,2048]
  const float* Wq_b     = (const float*)d_in[4];  // [2048]
  const float* Wk_w     = (const float*)d_in[5];  // [2048,2048]
  const float* Wk_b     = (const float*)d_in[6];  // [2048]
  const float* Wa_w     = (const float*)d_in[7];  // [196,2048]
  const float* Wa_b     = (const float*)d_in[8];  // [196]
  float* out = (float*)d_out;

  char* ws = (char*)d_ws;
  __bf16* semb = (__bf16*)ws;                   // 5120x2048 bf16 = 20,971,520 B
  __bf16* wqb  = (__bf16*)(ws + 20971520);      // 2048x2048 bf16 =  8,388,608 B
  __bf16* wkb  = (__bf16*)(ws + 29360128);      //                  8,388,608 B
  __bf16* wab  = (__bf16*)(ws + 37748736);      // 196x2048 bf16 =    802,816 B
  __bf16* Qb   = (__bf16*)(ws + 38551552);      // 5120x2048 bf16 = 20,971,520 B
  __bf16* Kb   = (__bf16*)(ws + 59523072);      //                 20,971,520 B
  float*  adj  = (float*)(ws + 80494592);       // 5120x196 f32  =  4,014,080 B
                                                // total 84,508,672 B

  // fp32 -> bf16 converts
  cvt_f32_bf16<<<(1310720 + 255) / 256, 256, 0, stream>>>(sem, semb, 1310720);
  cvt_f32_bf16<<<(524288 + 255) / 256, 256, 0, stream>>>(Wq_w, wqb, 524288);
  cvt_f32_bf16<<<(524288 + 255) / 256, 256, 0, stream>>>(Wk_w, wkb, 524288);
  cvt_f32_bf16<<<(50176 + 255) / 256, 256, 0, stream>>>(Wa_w, wab, 50176);

  // Q/K projections: [5120,2048] = semb @ W^T + b   (40 x 16 tiles)
  gemm_bt<0, false><<<640, 256, 0, stream>>>(semb, wqb, Wq_b, Qb, 2048, 2048, 40);
  gemm_bt<0, false><<<640, 256, 0, stream>>>(semb, wkb, Wk_b, Kb, 2048, 2048, 40);
  // adjust: sigmoid([5120,196] = semb @ Wa^T + b)   (40 x 2 tiles, N-guarded)
  gemm_bt<1, true><<<80, 256, 0, stream>>>(semb, wab, Wa_b, adj, 196, 2048, 40);

  // per-batch attention + fused epilogue
  attn_kernel<<<64, 256, 0, stream>>>(Qb, Kb, features, mask, adj, out);
}

// Round 2
// 212.218 us; speedup vs baseline: 1.5347x; 1.5347x over previous
//
#include <hip/hip_runtime.h>

typedef __bf16 bf16x8 __attribute__((ext_vector_type(8)));
typedef float f32x4 __attribute__((ext_vector_type(4)));

#define AS1 __attribute__((address_space(1)))
#define AS3 __attribute__((address_space(3)))

__device__ __forceinline__ void gload_lds16(const void* g, void* l) {
  __builtin_amdgcn_global_load_lds((const AS1 void*)g, (AS3 void*)l, 16, 0, 0);
}

// ---------------------------------------------------------------- fp32 -> bf16 (all 4 tensors, one dispatch)
// segments (vec8 units): sem 1310720 | wq 524288 | wk 524288 | wa 50176  => total 2409472
__global__ __launch_bounds__(256)
void cvt_all(const float* __restrict__ sem, const float* __restrict__ wq,
             const float* __restrict__ wk, const float* __restrict__ wa,
             __bf16* __restrict__ semb, __bf16* __restrict__ wcat) {
  int i = blockIdx.x * 256 + threadIdx.x;
  if (i >= 2409472) return;
  const float* in;
  __bf16* out;
  int j;
  if (i < 1310720) { in = sem; out = semb; j = i; }
  else if (i < 1835008) { in = wq; out = wcat; j = i - 1310720; }
  else if (i < 2359296) { in = wk; out = wcat + 4194304; j = i - 1835008; }
  else { in = wa; out = wcat + 8388608; j = i - 2359296; }
  const float4* p = (const float4*)in;
  float4 a = p[2 * j], b = p[2 * j + 1];
  bf16x8 v;
  v[0] = (__bf16)a.x; v[1] = (__bf16)a.y; v[2] = (__bf16)a.z; v[3] = (__bf16)a.w;
  v[4] = (__bf16)b.x; v[5] = (__bf16)b.y; v[6] = (__bf16)b.z; v[7] = (__bf16)b.w;
  *(bf16x8*)(out + (size_t)j * 8) = v;
}

// ---------------------------------------------------------------- fused projection GEMM
// C[5120, 4352] = semb[5120,2048] @ Wcat[4292,2048]^T (B rows clamped past 4291).
// Epilogue by column region: [0,2048) -> Qb (bf16, +Wq_b); [2048,4096) -> Kb (bf16, +Wk_b);
// [4096,4292) -> adj (fp32 sigmoid, +Wa_b); rest discarded.
__global__ __launch_bounds__(256)
void gemm_fused(const __bf16* __restrict__ A, const __bf16* __restrict__ B,
                const float* __restrict__ qbias, const float* __restrict__ kbias,
                const float* __restrict__ abias, __bf16* __restrict__ Qo,
                __bf16* __restrict__ Ko, float* __restrict__ adj) {
  __shared__ __bf16 sA[128 * 32];
  __shared__ __bf16 sB[128 * 32];
  const int bx = blockIdx.x;
  const int tm = bx % 40, tn = bx / 40;
  const int t = threadIdx.x;
  const int lane = t & 63;
  const int w = t >> 6, wm = w >> 1, wn = w & 1;

  f32x4 acc[4][4];
#pragma unroll
  for (int m = 0; m < 4; ++m)
#pragma unroll
    for (int n = 0; n < 4; ++n) acc[m][n] = (f32x4){0.f, 0.f, 0.f, 0.f};

  for (int k0 = 0; k0 < 2048; k0 += 32) {
#pragma unroll
    for (int s = 0; s < 2; ++s) {
      const int i = t + s * 256;
      const int row = i >> 2, cb = i & 3;
      gload_lds16(A + (size_t)(tm * 128 + row) * 2048 + k0 + cb * 8, sA + i * 8);
      int brow = tn * 128 + row;
      brow = brow < 4292 ? brow : 4291;
      gload_lds16(B + (size_t)brow * 2048 + k0 + cb * 8, sB + i * 8);
    }
    __syncthreads();
    bf16x8 af[4], bfr[4];
#pragma unroll
    for (int m = 0; m < 4; ++m)
      af[m] = *(const bf16x8*)(sA + (wm * 64 + m * 16 + (lane & 15)) * 32 + (lane >> 4) * 8);
#pragma unroll
    for (int n = 0; n < 4; ++n)
      bfr[n] = *(const bf16x8*)(sB + (wn * 64 + n * 16 + (lane & 15)) * 32 + (lane >> 4) * 8);
#pragma unroll
    for (int m = 0; m < 4; ++m)
#pragma unroll
      for (int n = 0; n < 4; ++n)
        acc[m][n] = __builtin_amdgcn_mfma_f32_16x16x32_bf16(af[m], bfr[n], acc[m][n], 0, 0, 0);
    __syncthreads();
  }

#pragma unroll
  for (int n = 0; n < 4; ++n) {
    const int col = tn * 128 + wn * 64 + n * 16 + (lane & 15);
    float bv;
    int region;  // 0=Q, 1=K, 2=adj, 3=discard
    if (col < 2048) { region = 0; bv = qbias[col]; }
    else if (col < 4096) { region = 1; bv = kbias[col - 2048]; }
    else if (col < 4292) { region = 2; bv = abias[col - 4096]; }
    else { region = 3; bv = 0.f; }
#pragma unroll
    for (int m = 0; m < 4; ++m) {
#pragma unroll
      for (int j = 0; j < 4; ++j) {
        if (region == 3) continue;
        const int row = tm * 128 + wm * 64 + m * 16 + (lane >> 4) * 4 + j;
        const float v = acc[m][n][j] + bv;
        if (region == 0)
          Qo[(size_t)row * 2048 + col] = (__bf16)v;
        else if (region == 1)
          Ko[(size_t)row * 2048 + (col - 2048)] = (__bf16)v;
        else
          adj[(size_t)row * 196 + (col - 4096)] = 1.f / (1.f + __expf(-v));
      }
    }
  }
}

// ---------------------------------------------------------------- attention
// One block per batch b. Phase1: S = Q_b K_b^T via MFMA (K-chunked LDS staging).
// Phase2: softmax(S*mask/sqrt(D)) rows. Phase3: context = P @ F via MFMA, fused epilogue.
__global__ __launch_bounds__(256)
void attn_kernel(const __bf16* __restrict__ Qb, const __bf16* __restrict__ Kb,
                 const float* __restrict__ feats, const float* __restrict__ mask,
                 const float* __restrict__ adj, float* __restrict__ out) {
  __shared__ char smem[107520];
  __bf16* sQ = (__bf16*)smem;                  // [80][256] bf16 (phase 1)
  __bf16* sK = (__bf16*)(smem + 40960);        // [80][256] bf16 (phase 1)
  float* S   = (float*)(smem + 81920);         // [80][80] fp32
  __bf16* Ft = (__bf16*)smem;                  // [208][96] bf16 (phase 3)
  __bf16* P  = (__bf16*)(smem + 40960);        // [80][96] bf16 (phase 3)

  const int b = blockIdx.x;
  const int t = threadIdx.x;
  const int lane = t & 63;
  const int w = t >> 6;

  const __bf16* Qbase = Qb + (size_t)b * 80 * 2048;
  const __bf16* Kbase = Kb + (size_t)b * 80 * 2048;

  // ---- Phase 1: S = Q K^T
  f32x4 acc[7];
#pragma unroll
  for (int u = 0; u < 7; ++u) acc[u] = (f32x4){0.f, 0.f, 0.f, 0.f};

  for (int kc = 0; kc < 2048; kc += 256) {
#pragma unroll
    for (int s = 0; s < 10; ++s) {
      const int i = t + s * 256;
      const int row = i >> 5, cb = i & 31;
      gload_lds16(Qbase + (size_t)row * 2048 + kc + cb * 8, sQ + i * 8);
    }
#pragma unroll
    for (int s = 0; s < 10; ++s) {
      const int i = t + s * 256;
      const int row = i >> 5, cb = i & 31;
      gload_lds16(Kbase + (size_t)row * 2048 + kc + cb * 8, sK + i * 8);
    }
    __syncthreads();
#pragma unroll
    for (int u = 0; u < 7; ++u) {
      const int tl = w + u * 4;
      if (tl < 25) {
        const int qi = tl / 5, kj = tl % 5;
#pragma unroll
        for (int k0 = 0; k0 < 256; k0 += 32) {
          bf16x8 a = *(const bf16x8*)(sQ + (qi * 16 + (lane & 15)) * 256 + k0 + (lane >> 4) * 8);
          bf16x8 kk = *(const bf16x8*)(sK + (kj * 16 + (lane & 15)) * 256 + k0 + (lane >> 4) * 8);
          acc[u] = __builtin_amdgcn_mfma_f32_16x16x32_bf16(a, kk, acc[u], 0, 0, 0);
        }
      }
    }
    __syncthreads();
  }
  // write S
#pragma unroll
  for (int u = 0; u < 7; ++u) {
    const int tl = w + u * 4;
    if (tl < 25) {
      const int qi = tl / 5, kj = tl % 5;
#pragma unroll
      for (int j = 0; j < 4; ++j) {
        const int r = qi * 16 + (lane >> 4) * 4 + j;
        const int c = kj * 16 + (lane & 15);
        S[r * 80 + c] = acc[u][j];
      }
    }
  }
  __syncthreads();

  // ---- Phase 2: softmax rows (threads 0..79) + stage F^T bf16 (all threads)
  if (t < 80) {
    const float scale = 0.02209708691207961f;  // 1/sqrt(2048)
    float mx = -1e30f;
    for (int k = 0; k < 80; ++k) {
      float v = S[t * 80 + k] * scale * mask[t * 80 + k];
      S[t * 80 + k] = v;
      mx = fmaxf(mx, v);
    }
    float sum = 0.f;
    for (int k = 0; k < 80; ++k) {
      float e = __expf(S[t * 80 + k] - mx);
      S[t * 80 + k] = e;
      sum += e;
    }
    const float r = 1.f / sum;
    for (int k = 0; k < 80; ++k) P[t * 96 + k] = (__bf16)(S[t * 80 + k] * r);
    for (int k = 80; k < 96; ++k) P[t * 96 + k] = (__bf16)0.f;  // zero K-pad
  }
  // stage F^T: Ft[h][k] = feats[b][k][h]  (k<80; pad cols k>=80 are killed by P==0)
  for (int idx = t; idx < 15680; idx += 256) {
    const int k = idx / 196, h = idx - k * 196;
    Ft[h * 96 + k] = (__bf16)feats[(size_t)b * 15680 + idx];
  }
  __syncthreads();

  // ---- Phase 3: context = P @ F, fused epilogue
  for (int u = 0; u < 17; ++u) {
    const int tl = w + u * 4;
    if (tl >= 65) break;
    const int ci = tl / 13, hj = tl - ci * 13;
    f32x4 a2 = (f32x4){0.f, 0.f, 0.f, 0.f};
#pragma unroll
    for (int k0 = 0; k0 < 96; k0 += 32) {
      bf16x8 pa = *(const bf16x8*)(P + (ci * 16 + (lane & 15)) * 96 + k0 + (lane >> 4) * 8);
      bf16x8 fb = *(const bf16x8*)(Ft + (hj * 16 + (lane & 15)) * 96 + k0 + (lane >> 4) * 8);
      a2 = __builtin_amdgcn_mfma_f32_16x16x32_bf16(pa, fb, a2, 0, 0, 0);
    }
#pragma unroll
    for (int j = 0; j < 4; ++j) {
      const int c = ci * 16 + (lane >> 4) * 4 + j;
      const int h = hj * 16 + (lane & 15);
      if (h < 196) {
        const size_t o = (size_t)b * 15680 + (size_t)c * 196 + h;
        out[o] = (feats[o] + a2[j]) * adj[o];
      }
    }
  }
}

// ---------------------------------------------------------------- launch
extern "C" void kernel_launch(void* const* d_in, const int* in_sizes, int n_in,
                              void* d_out, int out_size, void* d_ws, size_t ws_size,
                              hipStream_t stream) {
  const float* features = (const float*)d_in[0];  // [64,80,14,14]
  const float* sem      = (const float*)d_in[1];  // [64,80,2048]
  const float* mask     = (const float*)d_in[2];  // [80,80]
  const float* Wq_w     = (const float*)d_in[3];  // [2048,2048]
  const float* Wq_b     = (const float*)d_in[4];  // [2048]
  const float* Wk_w     = (const float*)d_in[5];  // [2048,2048]
  const float* Wk_b     = (const float*)d_in[6];  // [2048]
  const float* Wa_w     = (const float*)d_in[7];  // [196,2048]
  const float* Wa_b     = (const float*)d_in[8];  // [196]
  float* out = (float*)d_out;

  char* ws = (char*)d_ws;
  __bf16* semb = (__bf16*)ws;                   // 5120x2048 bf16 = 20,971,520 B
  __bf16* wcat = (__bf16*)(ws + 20971520);      // 4292x2048 bf16 = 17,580,032 B
  __bf16* Qb   = (__bf16*)(ws + 38551552);      // 5120x2048 bf16 = 20,971,520 B
  __bf16* Kb   = (__bf16*)(ws + 59523072);      //                 20,971,520 B
  float*  adj  = (float*)(ws + 80494592);       // 5120x196 f32  =  4,014,080 B
                                                // total 84,508,672 B

  // fp32 -> bf16 converts (one dispatch)
  cvt_all<<<9412, 256, 0, stream>>>(sem, Wq_w, Wk_w, Wa_w, semb, wcat);

  // fused Q/K/adjust projection: [5120,4352] tiles = 40 x 34
  gemm_fused<<<1360, 256, 0, stream>>>(semb, wcat, Wq_b, Wk_b, Wa_b, Qb, Kb, adj);

  // per-batch attention + fused epilogue
  attn_kernel<<<64, 256, 0, stream>>>(Qb, Kb, features, mask, adj, out);
}

// Round 3
// 176.717 us; speedup vs baseline: 1.8431x; 1.2009x over previous
//
#include <hip/hip_runtime.h>

typedef __bf16 bf16x8 __attribute__((ext_vector_type(8)));
typedef float f32x4 __attribute__((ext_vector_type(4)));

#define AS1 __attribute__((address_space(1)))
#define AS3 __attribute__((address_space(3)))

__device__ __forceinline__ void gload_lds16(const void* g, void* l) {
  __builtin_amdgcn_global_load_lds((const AS1 void*)g, (AS3 void*)l, 16, 0, 0);
}

#define MFMA16(a, b, c) __builtin_amdgcn_mfma_f32_16x16x32_bf16((a), (b), (c), 0, 0, 0)

// ---------------------------------------------------------------- fp32 -> bf16 (all 4 tensors, one dispatch)
// segments (vec8 units): sem 1310720 | wq 524288 | wk 524288 | wa 50176 => 2409472
__global__ __launch_bounds__(256)
void cvt_all(const float* __restrict__ sem, const float* __restrict__ wq,
             const float* __restrict__ wk, const float* __restrict__ wa,
             __bf16* __restrict__ semb, __bf16* __restrict__ wcat) {
  int i = blockIdx.x * 256 + threadIdx.x;
  if (i >= 2409472) return;
  const float* in;
  __bf16* out;
  int j;
  if (i < 1310720) { in = sem; out = semb; j = i; }
  else if (i < 1835008) { in = wq; out = wcat; j = i - 1310720; }
  else if (i < 2359296) { in = wk; out = wcat + 4194304; j = i - 1835008; }
  else { in = wa; out = wcat + 8388608; j = i - 2359296; }
  const float4* p = (const float4*)in;
  float4 a = p[2 * j], b = p[2 * j + 1];
  bf16x8 v;
  v[0] = (__bf16)a.x; v[1] = (__bf16)a.y; v[2] = (__bf16)a.z; v[3] = (__bf16)a.w;
  v[4] = (__bf16)b.x; v[5] = (__bf16)b.y; v[6] = (__bf16)b.z; v[7] = (__bf16)b.w;
  *(bf16x8*)(out + (size_t)j * 8) = v;
}

// ---------------------------------------------------------------- fused projection GEMM, 256x256 8-phase
// C[5120,4352] = semb[5120,2048] @ Wcat[4292,2048]^T (B rows clamped past 4291).
// cols [0,2048)->Qb bf16 +qb; [2048,4096)->Kb bf16 +kb; [4096,4292)->adj sigmoid; rest dropped.
// 512 thr = 8 waves (2M x 4N), BK=64, double-buffered 128KiB LDS, st-swizzled reads,
// counted vmcnt(4) pipeline (race-free stagger: B-halves(j+1)->other buf @ph1/2; A(j+2)->same buf @ph4).
__global__ __launch_bounds__(512, 2)
void gemm_fused(const __bf16* __restrict__ A, const __bf16* __restrict__ B,
                const float* __restrict__ qbias, const float* __restrict__ kbias,
                const float* __restrict__ abias, __bf16* __restrict__ Qo,
                __bf16* __restrict__ Ko, float* __restrict__ adj) {
  __shared__ char smem[131072];
  char* smc = smem;
  const int bx = blockIdx.x;
  const int tm = bx % 20, tn = bx / 20;
  const int t = threadIdx.x;
  const int lane = t & 63;
  const int w = t >> 6, wm = w >> 2, wn = w & 3;

  // staging constants (linear LDS dest; swizzle folded into global source column)
  const int r0 = t >> 3;                          // 0..63 (row within 64-row sub-half)
  const int colx = ((t & 7) ^ (r0 & 7)) * 8;      // pre-swizzled source column (elements)
  const int t16 = t * 16;
  const __bf16* Abase = A + (size_t)tm * 256 * 2048;

#define STAGE_A(kk, h, sbo) do {                                                        \
    const __bf16* gA = Abase + (size_t)((h) * 128 + r0) * 2048 + (kk) * 64 + colx;      \
    gload_lds16(gA, smc + (sbo) + (h) * 16384 + t16);                                   \
    gload_lds16(gA + (size_t)64 * 2048, smc + (sbo) + (h) * 16384 + 8192 + t16);        \
  } while (0)

#define STAGE_B(kk, h, sbo) do {                                                        \
    int br = tn * 256 + (h) * 128 + r0;                                                 \
    int br2 = br + 64;                                                                  \
    br = br < 4292 ? br : 4291;                                                         \
    br2 = br2 < 4292 ? br2 : 4291;                                                      \
    gload_lds16(B + (size_t)br * 2048 + (kk) * 64 + colx,                               \
                smc + (sbo) + 32768 + (h) * 16384 + t16);                               \
    gload_lds16(B + (size_t)br2 * 2048 + (kk) * 64 + colx,                              \
                smc + (sbo) + 32768 + (h) * 16384 + 8192 + t16);                        \
  } while (0)

  // fragment-read constants (swizzled ds_read)
  const int rbase = (lane & 15) * 128;
  const int g16 = (lane >> 4) * 16;
  const int x16 = (lane & 7) << 4;
  const int aoff = wm * 16384 + rbase;
  const int boff = 32768 + (wn >> 1) * 16384 + (wn & 1) * 8192 + rbase;

#define LDA(sb, m, kh) (*(const bf16x8*)(smc + (sb) + aoff + (m) * 2048 + (((kh) * 64 + g16) ^ x16)))
#define LDB(sb, n, kh) (*(const bf16x8*)(smc + (sb) + boff + (n) * 2048 + (((kh) * 64 + g16) ^ x16)))

  f32x4 acc[8][4];
#pragma unroll
  for (int m = 0; m < 8; ++m)
#pragma unroll
    for (int n = 0; n < 4; ++n) acc[m][n] = (f32x4){0.f, 0.f, 0.f, 0.f};

  // prologue: K0 fully + A-halves of K1
  STAGE_A(0, 0, 0); STAGE_A(0, 1, 0);
  STAGE_B(0, 0, 0); STAGE_B(0, 1, 0);
  STAGE_A(1, 0, 65536); STAGE_A(1, 1, 65536);
  asm volatile("s_waitcnt vmcnt(4)" ::: "memory");
  __builtin_amdgcn_s_barrier();

  for (int j = 0; j < 32; ++j) {
    const int sb = (j & 1) << 16, ob = sb ^ 65536;
    bf16x8 af[4][2], bf[2][2], bg[2][2];
    // ---- phase 1: quadrant (m0-3, n0-1)
#pragma unroll
    for (int m = 0; m < 4; ++m) { af[m][0] = LDA(sb, m, 0); af[m][1] = LDA(sb, m, 1); }
#pragma unroll
    for (int n = 0; n < 2; ++n) { bf[n][0] = LDB(sb, n, 0); bf[n][1] = LDB(sb, n, 1); }
    if (j < 31) STAGE_B(j + 1, 0, ob);
    __builtin_amdgcn_s_barrier();
    __builtin_amdgcn_s_setprio(1);
#pragma unroll
    for (int m = 0; m < 4; ++m)
#pragma unroll
      for (int n = 0; n < 2; ++n) {
        acc[m][n] = MFMA16(af[m][0], bf[n][0], acc[m][n]);
        acc[m][n] = MFMA16(af[m][1], bf[n][1], acc[m][n]);
      }
    __builtin_amdgcn_s_setprio(0);
    __builtin_amdgcn_s_barrier();
    // ---- phase 2: quadrant (m0-3, n2-3)
#pragma unroll
    for (int n = 0; n < 2; ++n) { bg[n][0] = LDB(sb, n + 2, 0); bg[n][1] = LDB(sb, n + 2, 1); }
    if (j < 31) STAGE_B(j + 1, 1, ob);
    __builtin_amdgcn_s_barrier();
    __builtin_amdgcn_s_setprio(1);
#pragma unroll
    for (int m = 0; m < 4; ++m)
#pragma unroll
      for (int n = 0; n < 2; ++n) {
        acc[m][n + 2] = MFMA16(af[m][0], bg[n][0], acc[m][n + 2]);
        acc[m][n + 2] = MFMA16(af[m][1], bg[n][1], acc[m][n + 2]);
      }
    __builtin_amdgcn_s_setprio(0);
    __builtin_amdgcn_s_barrier();
    // ---- phase 3: quadrant (m4-7, n2-3)
#pragma unroll
    for (int m = 0; m < 4; ++m) { af[m][0] = LDA(sb, m + 4, 0); af[m][1] = LDA(sb, m + 4, 1); }
    __builtin_amdgcn_s_barrier();
    __builtin_amdgcn_s_setprio(1);
#pragma unroll
    for (int m = 0; m < 4; ++m)
#pragma unroll
      for (int n = 0; n < 2; ++n) {
        acc[m + 4][n + 2] = MFMA16(af[m][0], bg[n][0], acc[m + 4][n + 2]);
        acc[m + 4][n + 2] = MFMA16(af[m][1], bg[n][1], acc[m + 4][n + 2]);
      }
    __builtin_amdgcn_s_setprio(0);
    __builtin_amdgcn_s_barrier();
    // ---- phase 4: quadrant (m4-7, n0-1); stage A(j+2) into same buf (A reads done @ph3)
#pragma unroll
    for (int n = 0; n < 2; ++n) { bf[n][0] = LDB(sb, n, 0); bf[n][1] = LDB(sb, n, 1); }
    if (j < 30) { STAGE_A(j + 2, 0, sb); STAGE_A(j + 2, 1, sb); }
    __builtin_amdgcn_s_barrier();
    __builtin_amdgcn_s_setprio(1);
#pragma unroll
    for (int m = 0; m < 4; ++m)
#pragma unroll
      for (int n = 0; n < 2; ++n) {
        acc[m + 4][n] = MFMA16(af[m][0], bf[n][0], acc[m + 4][n]);
        acc[m + 4][n] = MFMA16(af[m][1], bf[n][1], acc[m + 4][n]);
      }
    __builtin_amdgcn_s_setprio(0);
    if (j < 30) asm volatile("s_waitcnt vmcnt(4)" ::: "memory");
    else if (j == 30) asm volatile("s_waitcnt vmcnt(0)" ::: "memory");
    __builtin_amdgcn_s_barrier();
  }

  // ---- epilogue
  const int rowb = tm * 256 + wm * 128 + (lane >> 4) * 4;
  if (tn < 8) {
#pragma unroll
    for (int n = 0; n < 4; ++n) {
      const int col = tn * 256 + wn * 64 + n * 16 + (lane & 15);
      const float bv = qbias[col];
#pragma unroll
      for (int m = 0; m < 8; ++m)
#pragma unroll
        for (int jj = 0; jj < 4; ++jj)
          Qo[(size_t)(rowb + m * 16 + jj) * 2048 + col] = (__bf16)(acc[m][n][jj] + bv);
    }
  } else if (tn < 16) {
#pragma unroll
    for (int n = 0; n < 4; ++n) {
      const int col = (tn - 8) * 256 + wn * 64 + n * 16 + (lane & 15);
      const float bv = kbias[col];
#pragma unroll
      for (int m = 0; m < 8; ++m)
#pragma unroll
        for (int jj = 0; jj < 4; ++jj)
          Ko[(size_t)(rowb + m * 16 + jj) * 2048 + col] = (__bf16)(acc[m][n][jj] + bv);
    }
  } else {
#pragma unroll
    for (int n = 0; n < 4; ++n) {
      const int col = wn * 64 + n * 16 + (lane & 15);  // 0..255 within adj region
      if (col < 196) {
        const float bv = abias[col];
#pragma unroll
        for (int m = 0; m < 8; ++m)
#pragma unroll
          for (int jj = 0; jj < 4; ++jj) {
            const float v = acc[m][n][jj] + bv;
            adj[(size_t)(rowb + m * 16 + jj) * 196 + col] = 1.f / (1.f + __expf(-v));
          }
      }
    }
  }
#undef STAGE_A
#undef STAGE_B
#undef LDA
#undef LDB
}

// ---------------------------------------------------------------- attention 1/3: partial S
// grid (64 b x 4 kq): S_part[b][kq] = Q_b[:, kq*512..+512] @ K_b[...]^T  (f32 80x80)
__global__ __launch_bounds__(256)
void attn_s(const __bf16* __restrict__ Qb, const __bf16* __restrict__ Kb,
            float* __restrict__ Spart) {
  __shared__ char smem[81920];
  __bf16* sQ = (__bf16*)smem;            // [80][256]
  __bf16* sK = (__bf16*)(smem + 40960);  // [80][256]
  const int b = blockIdx.x >> 2, kq = blockIdx.x & 3;
  const int t = threadIdx.x, lane = t & 63, w = t >> 6;
  const __bf16* Qbase = Qb + (size_t)b * 163840;
  const __bf16* Kbase = Kb + (size_t)b * 163840;

  f32x4 acc[7];
#pragma unroll
  for (int u = 0; u < 7; ++u) acc[u] = (f32x4){0.f, 0.f, 0.f, 0.f};

  for (int kc = kq * 512; kc < kq * 512 + 512; kc += 256) {
#pragma unroll
    for (int s = 0; s < 10; ++s) {
      const int i = t + s * 256;
      const int row = i >> 5, cb = i & 31;
      gload_lds16(Qbase + (size_t)row * 2048 + kc + cb * 8, sQ + i * 8);
    }
#pragma unroll
    for (int s = 0; s < 10; ++s) {
      const int i = t + s * 256;
      const int row = i >> 5, cb = i & 31;
      gload_lds16(Kbase + (size_t)row * 2048 + kc + cb * 8, sK + i * 8);
    }
    __syncthreads();
#pragma unroll
    for (int u = 0; u < 7; ++u) {
      const int tl = w + u * 4;
      if (tl < 25) {
        const int qi = tl / 5, kj = tl % 5;
#pragma unroll
        for (int k0 = 0; k0 < 256; k0 += 32) {
          bf16x8 a = *(const bf16x8*)(sQ + (qi * 16 + (lane & 15)) * 256 + k0 + (lane >> 4) * 8);
          bf16x8 kk = *(const bf16x8*)(sK + (kj * 16 + (lane & 15)) * 256 + k0 + (lane >> 4) * 8);
          acc[u] = MFMA16(a, kk, acc[u]);
        }
      }
    }
    __syncthreads();
  }
  float* Sp = Spart + (size_t)(b * 4 + kq) * 6400;
#pragma unroll
  for (int u = 0; u < 7; ++u) {
    const int tl = w + u * 4;
    if (tl < 25) {
      const int qi = tl / 5, kj = tl % 5;
#pragma unroll
      for (int jj = 0; jj < 4; ++jj) {
        const int r = qi * 16 + (lane >> 4) * 4 + jj;
        const int c = kj * 16 + (lane & 15);
        Sp[r * 80 + c] = acc[u][jj];
      }
    }
  }
}

// ---------------------------------------------------------------- attention 2/3: softmax
// grid 64: sum 4 partials, softmax(S*scale*mask), write P bf16 [80][96] (zero-padded)
__global__ __launch_bounds__(256)
void attn_soft(const float* __restrict__ Spart, const float* __restrict__ mask,
               __bf16* __restrict__ Pg) {
  __shared__ float S[80 * 81];
  const int b = blockIdx.x, t = threadIdx.x;
  const float* Sp = Spart + (size_t)b * 4 * 6400;
  for (int idx = t; idx < 6400; idx += 256) {
    const int r = idx / 80, c = idx - r * 80;
    S[r * 81 + c] = Sp[idx] + Sp[6400 + idx] + Sp[12800 + idx] + Sp[19200 + idx];
  }
  __syncthreads();
  if (t < 80) {
    const float scale = 0.02209708691207961f;  // 1/sqrt(2048)
    float mx = -1e30f;
    for (int k = 0; k < 80; ++k) {
      float v = S[t * 81 + k] * scale * mask[t * 80 + k];
      S[t * 81 + k] = v;
      mx = fmaxf(mx, v);
    }
    float sum = 0.f;
    for (int k = 0; k < 80; ++k) {
      float e = __expf(S[t * 81 + k] - mx);
      S[t * 81 + k] = e;
      sum += e;
    }
    const float r = 1.f / sum;
    __bf16* Pr = Pg + (size_t)b * 7680 + t * 96;
    for (int k = 0; k < 80; ++k) Pr[k] = (__bf16)(S[t * 81 + k] * r);
    for (int k = 80; k < 96; ++k) Pr[k] = (__bf16)0.f;
  }
}

// ---------------------------------------------------------------- attention 3/3: PV + epilogue
// grid (64 b x 4 hq): ctx = P @ F[:, hq*49..+49]; out = (feats + ctx) * adj
__global__ __launch_bounds__(256)
void attn_pv(const __bf16* __restrict__ Pg, const float* __restrict__ feats,
             const float* __restrict__ adj, float* __restrict__ out) {
  __shared__ __bf16 Ft[64 * 104];  // [h'][k], stride 104 (bank-spread), k padded to 96
  const int b = blockIdx.x >> 2, hq = blockIdx.x & 3;
  const int hb = hq * 49;
  const int t = threadIdx.x, lane = t & 63, w = t >> 6;
  for (int idx = t; idx < 4704; idx += 256) {  // 96*49
    const int k = idx / 49, h = idx - k * 49;
    Ft[h * 104 + k] = (k < 80) ? (__bf16)feats[(size_t)b * 15680 + k * 196 + hb + h]
                               : (__bf16)0.f;
  }
  __syncthreads();
  const __bf16* Pb = Pg + (size_t)b * 7680;
#pragma unroll
  for (int u = 0; u < 5; ++u) {
    const int tl = w + u * 4;  // 0..19
    const int ci = tl >> 2, hj = tl & 3;
    f32x4 a2 = (f32x4){0.f, 0.f, 0.f, 0.f};
#pragma unroll
    for (int k0 = 0; k0 < 96; k0 += 32) {
      bf16x8 pa = *(const bf16x8*)(Pb + (ci * 16 + (lane & 15)) * 96 + k0 + (lane >> 4) * 8);
      bf16x8 fb = *(const bf16x8*)(Ft + (hj * 16 + (lane & 15)) * 104 + k0 + (lane >> 4) * 8);
      a2 = MFMA16(pa, fb, a2);
    }
#pragma unroll
    for (int jj = 0; jj < 4; ++jj) {
      const int c = ci * 16 + (lane >> 4) * 4 + jj;
      const int h2 = hj * 16 + (lane & 15);
      if (h2 < 49) {
        const size_t o = (size_t)b * 15680 + (size_t)c * 196 + hb + h2;
        out[o] = (feats[o] + a2[jj]) * adj[o];
      }
    }
  }
}

// ---------------------------------------------------------------- launch
extern "C" void kernel_launch(void* const* d_in, const int* in_sizes, int n_in,
                              void* d_out, int out_size, void* d_ws, size_t ws_size,
                              hipStream_t stream) {
  const float* features = (const float*)d_in[0];  // [64,80,14,14]
  const float* sem      = (const float*)d_in[1];  // [64,80,2048]
  const float* mask     = (const float*)d_in[2];  // [80,80]
  const float* Wq_w     = (const float*)d_in[3];
  const float* Wq_b     = (const float*)d_in[4];
  const float* Wk_w     = (const float*)d_in[5];
  const float* Wk_b     = (const float*)d_in[6];
  const float* Wa_w     = (const float*)d_in[7];
  const float* Wa_b     = (const float*)d_in[8];
  float* out = (float*)d_out;

  char* ws = (char*)d_ws;
  __bf16* semb = (__bf16*)ws;                   // 5120x2048 bf16 = 20,971,520 B
  __bf16* wcat = (__bf16*)(ws + 20971520);      // 4292x2048 bf16 = 17,580,032 B
  __bf16* Qb   = (__bf16*)(ws + 38551552);      // 20,971,520 B
  __bf16* Kb   = (__bf16*)(ws + 59523072);      // 20,971,520 B
  float*  adj  = (float*)(ws + 80494592);       // 5120x196 f32 = 4,014,080 B  (total 84.5 MB)
  // aliases of regions dead after gemm_fused:
  float*  Spart = (float*)ws;                   // 64*4*6400 f32 = 6,553,600 B (over semb)
  __bf16* Pg    = (__bf16*)(ws + 20971520);     // 64*80*96 bf16 = 983,040 B   (over wcat)

  cvt_all<<<9412, 256, 0, stream>>>(sem, Wq_w, Wk_w, Wa_w, semb, wcat);
  gemm_fused<<<340, 512, 0, stream>>>(semb, wcat, Wq_b, Wk_b, Wa_b, Qb, Kb, adj);
  attn_s<<<256, 256, 0, stream>>>(Qb, Kb, Spart);
  attn_soft<<<64, 256, 0, stream>>>(Spart, mask, Pg);
  attn_pv<<<256, 256, 0, stream>>>(Pg, features, adj, out);
}

// Round 4
// 175.599 us; speedup vs baseline: 1.8548x; 1.0064x over previous
//
#include <hip/hip_runtime.h>

typedef __bf16 bf16x8 __attribute__((ext_vector_type(8)));
typedef float f32x4 __attribute__((ext_vector_type(4)));

#define AS1 __attribute__((address_space(1)))
#define AS3 __attribute__((address_space(3)))

__device__ __forceinline__ void gload_lds16(const void* g, void* l) {
  __builtin_amdgcn_global_load_lds((const AS1 void*)g, (AS3 void*)l, 16, 0, 0);
}

#define MFMA16(a, b, c) __builtin_amdgcn_mfma_f32_16x16x32_bf16((a), (b), (c), 0, 0, 0)

// ---------------------------------------------------------------- fp32 -> bf16 (all 4 tensors, one dispatch)
__global__ __launch_bounds__(256)
void cvt_all(const float* __restrict__ sem, const float* __restrict__ wq,
             const float* __restrict__ wk, const float* __restrict__ wa,
             __bf16* __restrict__ semb, __bf16* __restrict__ wcat) {
  int i = blockIdx.x * 256 + threadIdx.x;
  if (i >= 2409472) return;
  const float* in;
  __bf16* out;
  int j;
  if (i < 1310720) { in = sem; out = semb; j = i; }
  else if (i < 1835008) { in = wq; out = wcat; j = i - 1310720; }
  else if (i < 2359296) { in = wk; out = wcat + 4194304; j = i - 1835008; }
  else { in = wa; out = wcat + 8388608; j = i - 2359296; }
  const float4* p = (const float4*)in;
  float4 a = p[2 * j], b = p[2 * j + 1];
  bf16x8 v;
  v[0] = (__bf16)a.x; v[1] = (__bf16)a.y; v[2] = (__bf16)a.z; v[3] = (__bf16)a.w;
  v[4] = (__bf16)b.x; v[5] = (__bf16)b.y; v[6] = (__bf16)b.z; v[7] = (__bf16)b.w;
  *(bf16x8*)(out + (size_t)j * 8) = v;
}

// ---------------------------------------------------------------- fused projection GEMM, 192x256 tiles
// C[5184(pad),4352] = semb[5120,2048] @ Wcat[4292,2048]^T (A rows clamp>=5120, B rows clamp>=4292).
// cols [0,2048)->Qb bf16 +qb; [2048,4096)->Kb bf16 +kb; [4096,4292)->adj sigmoid; rest dropped.
// 512 thr = 8 waves (2M x 4N). BK=64, NT=32. LDS: A dbuf 2x24KiB + B tribuf 3x32KiB = 144KiB.
// Schedule per iter j (4 phases, 2 barriers): ph1 stage A(j+1) [3+ phases cover],
// ph2/ph3 stage B(j+2) [5-6 phases cover], end-of-iter counted vmcnt(4) (never 0 in steady state).
__global__ __launch_bounds__(512, 2)
void gemm_fused(const __bf16* __restrict__ A, const __bf16* __restrict__ B,
                const float* __restrict__ qbias, const float* __restrict__ kbias,
                const float* __restrict__ abias, __bf16* __restrict__ Qo,
                __bf16* __restrict__ Ko, float* __restrict__ adj) {
  __shared__ char smem[147456];
  char* smc = smem;
  // bijective XCD swizzle (nwg=459, q=57, r=3), M-major => one XCD chunk shares a B panel
  const int bid = blockIdx.x;
  const int xcd = bid & 7, sidx = bid >> 3;
  const int wgid = (xcd < 3 ? xcd * 58 : 174 + (xcd - 3) * 57) + sidx;
  const int tm = wgid % 27, tn = wgid / 27;

  const int t = threadIdx.x;
  const int lane = t & 63;
  const int w = t >> 6, wm = w >> 2, wn = w & 3;

  // staging constants (linear LDS dest; swizzle folded into global source column)
  const int r0 = t >> 3;                       // 0..63
  const int colx = ((t & 7) ^ (r0 & 7)) * 8;   // pre-swizzled source column (elements)
  const int t16 = t * 16;

#define ABUF(kk) (smc + (((kk) & 1) ? 24576 : 0))
#define BBUF(kk) (smc + 49152 + ((kk) % 3) * 32768)

#define STAGE_A(kk) do {                                                     \
    char* dstA = ABUF(kk) + t16;                                             \
    int gr0 = tm * 192 + r0;        gr0 = gr0 < 5120 ? gr0 : 5119;           \
    int gr1 = tm * 192 + 64 + r0;   gr1 = gr1 < 5120 ? gr1 : 5119;           \
    int gr2 = tm * 192 + 128 + r0;  gr2 = gr2 < 5120 ? gr2 : 5119;           \
    gload_lds16(A + (size_t)gr0 * 2048 + (kk) * 64 + colx, dstA);            \
    gload_lds16(A + (size_t)gr1 * 2048 + (kk) * 64 + colx, dstA + 8192);     \
    gload_lds16(A + (size_t)gr2 * 2048 + (kk) * 64 + colx, dstA + 16384);    \
  } while (0)

#define STAGE_B01(kk) do {                                                   \
    char* dstB = BBUF(kk) + t16;                                             \
    int gr0 = tn * 256 + r0;        gr0 = gr0 < 4292 ? gr0 : 4291;           \
    int gr1 = tn * 256 + 64 + r0;   gr1 = gr1 < 4292 ? gr1 : 4291;           \
    gload_lds16(B + (size_t)gr0 * 2048 + (kk) * 64 + colx, dstB);            \
    gload_lds16(B + (size_t)gr1 * 2048 + (kk) * 64 + colx, dstB + 8192);     \
  } while (0)

#define STAGE_B23(kk) do {                                                   \
    char* dstB = BBUF(kk) + t16;                                             \
    int gr2 = tn * 256 + 128 + r0;  gr2 = gr2 < 4292 ? gr2 : 4291;           \
    int gr3 = tn * 256 + 192 + r0;  gr3 = gr3 < 4292 ? gr3 : 4291;           \
    gload_lds16(B + (size_t)gr2 * 2048 + (kk) * 64 + colx, dstB + 16384);    \
    gload_lds16(B + (size_t)gr3 * 2048 + (kk) * 64 + colx, dstB + 24576);    \
  } while (0)

  // fragment-read constants (swizzled ds_read)
  const int rbase = (lane & 15) * 128;
  const int g16 = (lane >> 4) * 16;
  const int x16 = (lane & 7) << 4;
  const int aoff = wm * 12288 + rbase;  // wm*96 rows * 128B
  const int boff = wn * 8192 + rbase;   // wn*64 rows * 128B

#define LDA(ab, m, kh) (*(const bf16x8*)((ab) + aoff + (m) * 2048 + ((((kh) * 64) + g16) ^ x16)))
#define LDB(bb, n, kh) (*(const bf16x8*)((bb) + boff + (n) * 2048 + ((((kh) * 64) + g16) ^ x16)))

  f32x4 acc[6][4];
#pragma unroll
  for (int m = 0; m < 6; ++m)
#pragma unroll
    for (int n = 0; n < 4; ++n) acc[m][n] = (f32x4){0.f, 0.f, 0.f, 0.f};

  // prologue: A(0), B(0), B(1); force A(0)+B(0) (oldest 7), leave B(1) in flight
  STAGE_A(0);
  STAGE_B01(0); STAGE_B23(0);
  STAGE_B01(1); STAGE_B23(1);
  asm volatile("s_waitcnt vmcnt(4)" ::: "memory");
  __builtin_amdgcn_s_barrier();

  for (int j = 0; j < 32; ++j) {
    char* Ab = ABUF(j);
    char* Bb = BBUF(j);
    bf16x8 af[3][2], ag[3][2], bf[2][2], bg[2][2];
    // ---- ph1: quadrant (m0-2, n0-1); stage A(j+1)
#pragma unroll
    for (int m = 0; m < 3; ++m) { af[m][0] = LDA(Ab, m, 0); af[m][1] = LDA(Ab, m, 1); }
#pragma unroll
    for (int n = 0; n < 2; ++n) { bf[n][0] = LDB(Bb, n, 0); bf[n][1] = LDB(Bb, n, 1); }
    if (j < 31) STAGE_A(j + 1);
    __builtin_amdgcn_s_setprio(1);
#pragma unroll
    for (int m = 0; m < 3; ++m)
#pragma unroll
      for (int n = 0; n < 2; ++n) {
        acc[m][n] = MFMA16(af[m][0], bf[n][0], acc[m][n]);
        acc[m][n] = MFMA16(af[m][1], bf[n][1], acc[m][n]);
      }
    __builtin_amdgcn_s_setprio(0);
    // ---- ph2: quadrant (m0-2, n2-3); stage B01(j+2)
#pragma unroll
    for (int n = 0; n < 2; ++n) { bg[n][0] = LDB(Bb, n + 2, 0); bg[n][1] = LDB(Bb, n + 2, 1); }
    if (j < 30) STAGE_B01(j + 2);
    __builtin_amdgcn_s_setprio(1);
#pragma unroll
    for (int m = 0; m < 3; ++m)
#pragma unroll
      for (int n = 0; n < 2; ++n) {
        acc[m][n + 2] = MFMA16(af[m][0], bg[n][0], acc[m][n + 2]);
        acc[m][n + 2] = MFMA16(af[m][1], bg[n][1], acc[m][n + 2]);
      }
    __builtin_amdgcn_s_setprio(0);
    __builtin_amdgcn_s_barrier();  // barrier 1 (end window {ph1,ph2})
    // ---- ph3: quadrant (m3-5, n2-3); stage B23(j+2)
#pragma unroll
    for (int m = 0; m < 3; ++m) { ag[m][0] = LDA(Ab, m + 3, 0); ag[m][1] = LDA(Ab, m + 3, 1); }
    if (j < 30) STAGE_B23(j + 2);
    __builtin_amdgcn_s_setprio(1);
#pragma unroll
    for (int m = 0; m < 3; ++m)
#pragma unroll
      for (int n = 0; n < 2; ++n) {
        acc[m + 3][n + 2] = MFMA16(ag[m][0], bg[n][0], acc[m + 3][n + 2]);
        acc[m + 3][n + 2] = MFMA16(ag[m][1], bg[n][1], acc[m + 3][n + 2]);
      }
    __builtin_amdgcn_s_setprio(0);
    // ---- ph4: quadrant (m3-5, n0-1); bf regs held from ph1 (no LDS re-read)
    __builtin_amdgcn_s_setprio(1);
#pragma unroll
    for (int m = 0; m < 3; ++m)
#pragma unroll
      for (int n = 0; n < 2; ++n) {
        acc[m + 3][n] = MFMA16(ag[m][0], bf[n][0], acc[m + 3][n]);
        acc[m + 3][n] = MFMA16(ag[m][1], bf[n][1], acc[m + 3][n]);
      }
    __builtin_amdgcn_s_setprio(0);
    // counted wait: force A(j+1)+B(j+1) landed, leave B(j+2) (4 loads) in flight
    if (j < 30) asm volatile("s_waitcnt vmcnt(4)" ::: "memory");
    else if (j == 30) asm volatile("s_waitcnt vmcnt(0)" ::: "memory");
    __builtin_amdgcn_s_barrier();  // barrier 2 (end window {ph3,ph4})
  }

  // ---- epilogue
  const int rowb = tm * 192 + wm * 96 + (lane >> 4) * 4;
#pragma unroll
  for (int n = 0; n < 4; ++n) {
    const int col = tn * 256 + wn * 64 + n * 16 + (lane & 15);
    int region;  // 0=Q, 1=K, 2=adj, 3=discard
    float bv;
    if (col < 2048) { region = 0; bv = qbias[col]; }
    else if (col < 4096) { region = 1; bv = kbias[col - 2048]; }
    else if (col < 4292) { region = 2; bv = abias[col - 4096]; }
    else { region = 3; bv = 0.f; }
#pragma unroll
    for (int m = 0; m < 6; ++m)
#pragma unroll
      for (int jj = 0; jj < 4; ++jj) {
        const int row = rowb + m * 16 + jj;
        if (region == 3 || row >= 5120) continue;
        const float v = acc[m][n][jj] + bv;
        if (region == 0)
          Qo[(size_t)row * 2048 + col] = (__bf16)v;
        else if (region == 1)
          Ko[(size_t)row * 2048 + (col - 2048)] = (__bf16)v;
        else
          adj[(size_t)row * 196 + (col - 4096)] = 1.f / (1.f + __expf(-v));
      }
  }
#undef ABUF
#undef BBUF
#undef STAGE_A
#undef STAGE_B01
#undef STAGE_B23
#undef LDA
#undef LDB
}

// ---------------------------------------------------------------- attention 1/3: partial S
__global__ __launch_bounds__(256)
void attn_s(const __bf16* __restrict__ Qb, const __bf16* __restrict__ Kb,
            float* __restrict__ Spart) {
  __shared__ char smem[81920];
  __bf16* sQ = (__bf16*)smem;            // [80][256]
  __bf16* sK = (__bf16*)(smem + 40960);  // [80][256]
  const int b = blockIdx.x >> 2, kq = blockIdx.x & 3;
  const int t = threadIdx.x, lane = t & 63, w = t >> 6;
  const __bf16* Qbase = Qb + (size_t)b * 163840;
  const __bf16* Kbase = Kb + (size_t)b * 163840;

  f32x4 acc[7];
#pragma unroll
  for (int u = 0; u < 7; ++u) acc[u] = (f32x4){0.f, 0.f, 0.f, 0.f};

  for (int kc = kq * 512; kc < kq * 512 + 512; kc += 256) {
#pragma unroll
    for (int s = 0; s < 10; ++s) {
      const int i = t + s * 256;
      const int row = i >> 5, cb = i & 31;
      gload_lds16(Qbase + (size_t)row * 2048 + kc + cb * 8, sQ + i * 8);
    }
#pragma unroll
    for (int s = 0; s < 10; ++s) {
      const int i = t + s * 256;
      const int row = i >> 5, cb = i & 31;
      gload_lds16(Kbase + (size_t)row * 2048 + kc + cb * 8, sK + i * 8);
    }
    __syncthreads();
#pragma unroll
    for (int u = 0; u < 7; ++u) {
      const int tl = w + u * 4;
      if (tl < 25) {
        const int qi = tl / 5, kj = tl % 5;
#pragma unroll
        for (int k0 = 0; k0 < 256; k0 += 32) {
          bf16x8 a = *(const bf16x8*)(sQ + (qi * 16 + (lane & 15)) * 256 + k0 + (lane >> 4) * 8);
          bf16x8 kk = *(const bf16x8*)(sK + (kj * 16 + (lane & 15)) * 256 + k0 + (lane >> 4) * 8);
          acc[u] = MFMA16(a, kk, acc[u]);
        }
      }
    }
    __syncthreads();
  }
  float* Sp = Spart + (size_t)(b * 4 + kq) * 6400;
#pragma unroll
  for (int u = 0; u < 7; ++u) {
    const int tl = w + u * 4;
    if (tl < 25) {
      const int qi = tl / 5, kj = tl % 5;
#pragma unroll
      for (int jj = 0; jj < 4; ++jj) {
        const int r = qi * 16 + (lane >> 4) * 4 + jj;
        const int c = kj * 16 + (lane & 15);
        Sp[r * 80 + c] = acc[u][jj];
      }
    }
  }
}

// ---------------------------------------------------------------- attention 2/3: softmax
__global__ __launch_bounds__(256)
void attn_soft(const float* __restrict__ Spart, const float* __restrict__ mask,
               __bf16* __restrict__ Pg) {
  __shared__ float S[80 * 81];
  const int b = blockIdx.x, t = threadIdx.x;
  const float* Sp = Spart + (size_t)b * 4 * 6400;
  for (int idx = t; idx < 6400; idx += 256) {
    const int r = idx / 80, c = idx - r * 80;
    S[r * 81 + c] = Sp[idx] + Sp[6400 + idx] + Sp[12800 + idx] + Sp[19200 + idx];
  }
  __syncthreads();
  if (t < 80) {
    const float scale = 0.02209708691207961f;  // 1/sqrt(2048)
    float mx = -1e30f;
    for (int k = 0; k < 80; ++k) {
      float v = S[t * 81 + k] * scale * mask[t * 80 + k];
      S[t * 81 + k] = v;
      mx = fmaxf(mx, v);
    }
    float sum = 0.f;
    for (int k = 0; k < 80; ++k) {
      float e = __expf(S[t * 81 + k] - mx);
      S[t * 81 + k] = e;
      sum += e;
    }
    const float r = 1.f / sum;
    __bf16* Pr = Pg + (size_t)b * 7680 + t * 96;
    for (int k = 0; k < 80; ++k) Pr[k] = (__bf16)(S[t * 81 + k] * r);
    for (int k = 80; k < 96; ++k) Pr[k] = (__bf16)0.f;
  }
}

// ---------------------------------------------------------------- attention 3/3: PV + epilogue
__global__ __launch_bounds__(256)
void attn_pv(const __bf16* __restrict__ Pg, const float* __restrict__ feats,
             const float* __restrict__ adj, float* __restrict__ out) {
  __shared__ __bf16 Ft[64 * 104];
  const int b = blockIdx.x >> 2, hq = blockIdx.x & 3;
  const int hb = hq * 49;
  const int t = threadIdx.x, lane = t & 63, w = t >> 6;
  for (int idx = t; idx < 4704; idx += 256) {  // 96*49
    const int k = idx / 49, h = idx - k * 49;
    Ft[h * 104 + k] = (k < 80) ? (__bf16)feats[(size_t)b * 15680 + k * 196 + hb + h]
                               : (__bf16)0.f;
  }
  __syncthreads();
  const __bf16* Pb = Pg + (size_t)b * 7680;
#pragma unroll
  for (int u = 0; u < 5; ++u) {
    const int tl = w + u * 4;  // 0..19
    const int ci = tl >> 2, hj = tl & 3;
    f32x4 a2 = (f32x4){0.f, 0.f, 0.f, 0.f};
#pragma unroll
    for (int k0 = 0; k0 < 96; k0 += 32) {
      bf16x8 pa = *(const bf16x8*)(Pb + (ci * 16 + (lane & 15)) * 96 + k0 + (lane >> 4) * 8);
      bf16x8 fb = *(const bf16x8*)(Ft + (hj * 16 + (lane & 15)) * 104 + k0 + (lane >> 4) * 8);
      a2 = MFMA16(pa, fb, a2);
    }
#pragma unroll
    for (int jj = 0; jj < 4; ++jj) {
      const int c = ci * 16 + (lane >> 4) * 4 + jj;
      const int h2 = hj * 16 + (lane & 15);
      if (h2 < 49) {
        const size_t o = (size_t)b * 15680 + (size_t)c * 196 + hb + h2;
        out[o] = (feats[o] + a2[jj]) * adj[o];
      }
    }
  }
}

// ---------------------------------------------------------------- launch
extern "C" void kernel_launch(void* const* d_in, const int* in_sizes, int n_in,
                              void* d_out, int out_size, void* d_ws, size_t ws_size,
                              hipStream_t stream) {
  const float* features = (const float*)d_in[0];
  const float* sem      = (const float*)d_in[1];
  const float* mask     = (const float*)d_in[2];
  const float* Wq_w     = (const float*)d_in[3];
  const float* Wq_b     = (const float*)d_in[4];
  const float* Wk_w     = (const float*)d_in[5];
  const float* Wk_b     = (const float*)d_in[6];
  const float* Wa_w     = (const float*)d_in[7];
  const float* Wa_b     = (const float*)d_in[8];
  float* out = (float*)d_out;

  char* ws = (char*)d_ws;
  __bf16* semb = (__bf16*)ws;                   // 5120x2048 bf16
  __bf16* wcat = (__bf16*)(ws + 20971520);      // 4292x2048 bf16
  __bf16* Qb   = (__bf16*)(ws + 38551552);
  __bf16* Kb   = (__bf16*)(ws + 59523072);
  float*  adj  = (float*)(ws + 80494592);       // 5120x196 f32 (total 84.5 MB)
  float*  Spart = (float*)ws;                   // aliases semb (dead after gemm)
  __bf16* Pg    = (__bf16*)(ws + 20971520);     // aliases wcat (dead after gemm)

  cvt_all<<<9412, 256, 0, stream>>>(sem, Wq_w, Wk_w, Wa_w, semb, wcat);
  gemm_fused<<<459, 512, 0, stream>>>(semb, wcat, Wq_b, Wk_b, Wa_b, Qb, Kb, adj);
  attn_s<<<256, 256, 0, stream>>>(Qb, Kb, Spart);
  attn_soft<<<64, 256, 0, stream>>>(Spart, mask, Pg);
  attn_pv<<<256, 256, 0, stream>>>(Pg, features, adj, out);
}

// Round 5
// 159.979 us; speedup vs baseline: 2.0359x; 1.0976x over previous
//
#include <hip/hip_runtime.h>

typedef __bf16 bf16x8 __attribute__((ext_vector_type(8)));
typedef float f32x4 __attribute__((ext_vector_type(4)));

#define AS1 __attribute__((address_space(1)))
#define AS3 __attribute__((address_space(3)))

__device__ __forceinline__ void gload_lds16(const void* g, void* l) {
  __builtin_amdgcn_global_load_lds((const AS1 void*)g, (AS3 void*)l, 16, 0, 0);
}

#define MFMA16(a, b, c) __builtin_amdgcn_mfma_f32_16x16x32_bf16((a), (b), (c), 0, 0, 0)

// ---------------------------------------------------------------- fp32 -> bf16 (all 4 tensors, one dispatch)
__global__ __launch_bounds__(256)
void cvt_all(const float* __restrict__ sem, const float* __restrict__ wq,
             const float* __restrict__ wk, const float* __restrict__ wa,
             __bf16* __restrict__ semb, __bf16* __restrict__ wcat) {
  int i = blockIdx.x * 256 + threadIdx.x;
  if (i >= 2409472) return;
  const float* in;
  __bf16* out;
  int j;
  if (i < 1310720) { in = sem; out = semb; j = i; }
  else if (i < 1835008) { in = wq; out = wcat; j = i - 1310720; }
  else if (i < 2359296) { in = wk; out = wcat + 4194304; j = i - 1835008; }
  else { in = wa; out = wcat + 8388608; j = i - 2359296; }
  const float4* p = (const float4*)in;
  float4 a = p[2 * j], b = p[2 * j + 1];
  bf16x8 v;
  v[0] = (__bf16)a.x; v[1] = (__bf16)a.y; v[2] = (__bf16)a.z; v[3] = (__bf16)a.w;
  v[4] = (__bf16)b.x; v[5] = (__bf16)b.y; v[6] = (__bf16)b.z; v[7] = (__bf16)b.w;
  *(bf16x8*)(out + (size_t)j * 8) = v;
}

// ---------------------------------------------------------------- fused projection GEMM, 192x256 tiles
// C[5184(pad),4352] = semb[5120,2048] @ Wcat[4292,2048]^T.
// cols [0,2048)->Qb bf16 +qb; [2048,4096)->Kb bf16 +kb; [4096,4292)->adj sigmoid.
// 512 thr = 8 waves (2M x 4N). BK=64. LDS: A dbuf 2x24KiB + B tribuf 3x32KiB = 144KiB.
// Pipeline: ph1 stage A(j+1), ph2/ph3 stage B(j+2); end-of-iter counted vmcnt(4).
// Epilogue (tn<16): acc -> bf16 LDS tile [192][264] -> coalesced 16B row-major stores.
__global__ __launch_bounds__(512, 2)
void gemm_fused(const __bf16* __restrict__ A, const __bf16* __restrict__ B,
                const float* __restrict__ qbias, const float* __restrict__ kbias,
                const float* __restrict__ abias, __bf16* __restrict__ Qo,
                __bf16* __restrict__ Ko, float* __restrict__ adj) {
  __shared__ char smem[147456];
  char* smc = smem;
  // bijective XCD chunking (nwg=459, q=57, r=3) + 4-wide tn-band, tm-major in band
  const int bid = blockIdx.x;
  const int xcd = bid & 7, sidx = bid >> 3;
  const int wgid = (xcd < 3 ? xcd * 58 : 174 + (xcd - 3) * 57) + sidx;
  int tm, tn;
  if (wgid < 432) {
    const int band = wgid / 108, rem = wgid % 108;
    tm = rem >> 2;
    tn = band * 4 + (rem & 3);
  } else {
    tm = wgid - 432;
    tn = 16;
  }

  const int t = threadIdx.x;
  const int lane = t & 63;
  const int w = t >> 6, wm = w >> 2, wn = w & 3;

  // staging constants (linear LDS dest; swizzle folded into global source column)
  const int r0 = t >> 3;                       // 0..63
  const int colx = ((t & 7) ^ (r0 & 7)) * 8;   // pre-swizzled source column (elements)
  const int t16 = t * 16;

#define ABUF(kk) (smc + (((kk) & 1) ? 24576 : 0))
#define BBUF(kk) (smc + 49152 + ((kk) % 3) * 32768)

#define STAGE_A(kk) do {                                                     \
    char* dstA = ABUF(kk) + t16;                                             \
    int gr0 = tm * 192 + r0;        gr0 = gr0 < 5120 ? gr0 : 5119;           \
    int gr1 = tm * 192 + 64 + r0;   gr1 = gr1 < 5120 ? gr1 : 5119;           \
    int gr2 = tm * 192 + 128 + r0;  gr2 = gr2 < 5120 ? gr2 : 5119;           \
    gload_lds16(A + (size_t)gr0 * 2048 + (kk) * 64 + colx, dstA);            \
    gload_lds16(A + (size_t)gr1 * 2048 + (kk) * 64 + colx, dstA + 8192);     \
    gload_lds16(A + (size_t)gr2 * 2048 + (kk) * 64 + colx, dstA + 16384);    \
  } while (0)

#define STAGE_B01(kk) do {                                                   \
    char* dstB = BBUF(kk) + t16;                                             \
    int gr0 = tn * 256 + r0;        gr0 = gr0 < 4292 ? gr0 : 4291;           \
    int gr1 = tn * 256 + 64 + r0;   gr1 = gr1 < 4292 ? gr1 : 4291;           \
    gload_lds16(B + (size_t)gr0 * 2048 + (kk) * 64 + colx, dstB);            \
    gload_lds16(B + (size_t)gr1 * 2048 + (kk) * 64 + colx, dstB + 8192);     \
  } while (0)

#define STAGE_B23(kk) do {                                                   \
    char* dstB = BBUF(kk) + t16;                                             \
    int gr2 = tn * 256 + 128 + r0;  gr2 = gr2 < 4292 ? gr2 : 4291;           \
    int gr3 = tn * 256 + 192 + r0;  gr3 = gr3 < 4292 ? gr3 : 4291;           \
    gload_lds16(B + (size_t)gr2 * 2048 + (kk) * 64 + colx, dstB + 16384);    \
    gload_lds16(B + (size_t)gr3 * 2048 + (kk) * 64 + colx, dstB + 24576);    \
  } while (0)

  // fragment-read constants (swizzled ds_read)
  const int rbase = (lane & 15) * 128;
  const int g16 = (lane >> 4) * 16;
  const int x16 = (lane & 7) << 4;
  const int aoff = wm * 12288 + rbase;  // wm*96 rows * 128B
  const int boff = wn * 8192 + rbase;   // wn*64 rows * 128B

#define LDA(ab, m, kh) (*(const bf16x8*)((ab) + aoff + (m) * 2048 + ((((kh) * 64) + g16) ^ x16)))
#define LDB(bb, n, kh) (*(const bf16x8*)((bb) + boff + (n) * 2048 + ((((kh) * 64) + g16) ^ x16)))

  f32x4 acc[6][4];
#pragma unroll
  for (int m = 0; m < 6; ++m)
#pragma unroll
    for (int n = 0; n < 4; ++n) acc[m][n] = (f32x4){0.f, 0.f, 0.f, 0.f};

  // prologue
  STAGE_A(0);
  STAGE_B01(0); STAGE_B23(0);
  STAGE_B01(1); STAGE_B23(1);
  asm volatile("s_waitcnt vmcnt(4)" ::: "memory");
  __builtin_amdgcn_s_barrier();

  for (int j = 0; j < 32; ++j) {
    char* Ab = ABUF(j);
    char* Bb = BBUF(j);
    bf16x8 af[3][2], ag[3][2], bf[2][2], bg[2][2];
    // ---- ph1: (m0-2, n0-1); stage A(j+1)
#pragma unroll
    for (int m = 0; m < 3; ++m) { af[m][0] = LDA(Ab, m, 0); af[m][1] = LDA(Ab, m, 1); }
#pragma unroll
    for (int n = 0; n < 2; ++n) { bf[n][0] = LDB(Bb, n, 0); bf[n][1] = LDB(Bb, n, 1); }
    if (j < 31) STAGE_A(j + 1);
    __builtin_amdgcn_s_setprio(1);
#pragma unroll
    for (int m = 0; m < 3; ++m)
#pragma unroll
      for (int n = 0; n < 2; ++n) {
        acc[m][n] = MFMA16(af[m][0], bf[n][0], acc[m][n]);
        acc[m][n] = MFMA16(af[m][1], bf[n][1], acc[m][n]);
      }
    __builtin_amdgcn_s_setprio(0);
    // ---- ph2: (m0-2, n2-3); stage B01(j+2)
#pragma unroll
    for (int n = 0; n < 2; ++n) { bg[n][0] = LDB(Bb, n + 2, 0); bg[n][1] = LDB(Bb, n + 2, 1); }
    if (j < 30) STAGE_B01(j + 2);
    __builtin_amdgcn_s_setprio(1);
#pragma unroll
    for (int m = 0; m < 3; ++m)
#pragma unroll
      for (int n = 0; n < 2; ++n) {
        acc[m][n + 2] = MFMA16(af[m][0], bg[n][0], acc[m][n + 2]);
        acc[m][n + 2] = MFMA16(af[m][1], bg[n][1], acc[m][n + 2]);
      }
    __builtin_amdgcn_s_setprio(0);
    __builtin_amdgcn_s_barrier();  // barrier 1
    // ---- ph3: (m3-5, n2-3); stage B23(j+2)
#pragma unroll
    for (int m = 0; m < 3; ++m) { ag[m][0] = LDA(Ab, m + 3, 0); ag[m][1] = LDA(Ab, m + 3, 1); }
    if (j < 30) STAGE_B23(j + 2);
    __builtin_amdgcn_s_setprio(1);
#pragma unroll
    for (int m = 0; m < 3; ++m)
#pragma unroll
      for (int n = 0; n < 2; ++n) {
        acc[m + 3][n + 2] = MFMA16(ag[m][0], bg[n][0], acc[m + 3][n + 2]);
        acc[m + 3][n + 2] = MFMA16(ag[m][1], bg[n][1], acc[m + 3][n + 2]);
      }
    __builtin_amdgcn_s_setprio(0);
    // ---- ph4: (m3-5, n0-1); bf regs held from ph1
    __builtin_amdgcn_s_setprio(1);
#pragma unroll
    for (int m = 0; m < 3; ++m)
#pragma unroll
      for (int n = 0; n < 2; ++n) {
        acc[m + 3][n] = MFMA16(ag[m][0], bf[n][0], acc[m + 3][n]);
        acc[m + 3][n] = MFMA16(ag[m][1], bf[n][1], acc[m + 3][n]);
      }
    __builtin_amdgcn_s_setprio(0);
    if (j < 30) asm volatile("s_waitcnt vmcnt(4)" ::: "memory");
    else if (j == 30) asm volatile("s_waitcnt vmcnt(0)" ::: "memory");
    __builtin_amdgcn_s_barrier();  // barrier 2
  }

  // ---- epilogue
  if (tn < 16) {
    // bias-add + bf16 convert into LDS [192][264] (row stride 528 B), then coalesced stores
    __bf16* so = (__bf16*)smc;
    const float* bias = (tn < 8) ? (qbias + tn * 256) : (kbias + (tn - 8) * 256);
#pragma unroll
    for (int n = 0; n < 4; ++n) {
      const int colb = wn * 64 + n * 16 + (lane & 15);
      const float bv = bias[colb];
#pragma unroll
      for (int m = 0; m < 6; ++m) {
        const int row = wm * 96 + m * 16 + (lane >> 4) * 4;
#pragma unroll
        for (int jj = 0; jj < 4; ++jj)
          so[(row + jj) * 264 + colb] = (__bf16)(acc[m][n][jj] + bv);
      }
    }
    __syncthreads();
    __bf16* dst = (tn < 8) ? (Qo + tn * 256) : (Ko + (tn - 8) * 256);
    for (int idx = t; idx < 6144; idx += 512) {  // 192 rows x 32 16B-chunks
      const int row = idx >> 5, c = idx & 31;
      const int grow = tm * 192 + row;
      if (grow < 5120) {
        bf16x8 v = *(const bf16x8*)(so + row * 264 + c * 8);
        *(bf16x8*)(dst + (size_t)grow * 2048 + c * 8) = v;
      }
    }
  } else {
    // adj region (cols 4096..4291): scattered f32 sigmoid stores (small, 4 MB)
    const int rowb = tm * 192 + wm * 96 + (lane >> 4) * 4;
#pragma unroll
    for (int n = 0; n < 4; ++n) {
      const int col = wn * 64 + n * 16 + (lane & 15);  // 0..255 within adj region
      if (col < 196) {
        const float bv = abias[col];
#pragma unroll
        for (int m = 0; m < 6; ++m)
#pragma unroll
          for (int jj = 0; jj < 4; ++jj) {
            const int row = rowb + m * 16 + jj;
            if (row < 5120) {
              const float v = acc[m][n][jj] + bv;
              adj[(size_t)row * 196 + col] = 1.f / (1.f + __expf(-v));
            }
          }
      }
    }
  }
#undef ABUF
#undef BBUF
#undef STAGE_A
#undef STAGE_B01
#undef STAGE_B23
#undef LDA
#undef LDB
}

// ---------------------------------------------------------------- attention 1/3: partial S
__global__ __launch_bounds__(256)
void attn_s(const __bf16* __restrict__ Qb, const __bf16* __restrict__ Kb,
            float* __restrict__ Spart) {
  __shared__ char smem[81920];
  __bf16* sQ = (__bf16*)smem;            // [80][256]
  __bf16* sK = (__bf16*)(smem + 40960);  // [80][256]
  const int b = blockIdx.x >> 2, kq = blockIdx.x & 3;
  const int t = threadIdx.x, lane = t & 63, w = t >> 6;
  const __bf16* Qbase = Qb + (size_t)b * 163840;
  const __bf16* Kbase = Kb + (size_t)b * 163840;

  f32x4 acc[7];
#pragma unroll
  for (int u = 0; u < 7; ++u) acc[u] = (f32x4){0.f, 0.f, 0.f, 0.f};

  for (int kc = kq * 512; kc < kq * 512 + 512; kc += 256) {
#pragma unroll
    for (int s = 0; s < 10; ++s) {
      const int i = t + s * 256;
      const int row = i >> 5, cb = i & 31;
      gload_lds16(Qbase + (size_t)row * 2048 + kc + cb * 8, sQ + i * 8);
    }
#pragma unroll
    for (int s = 0; s < 10; ++s) {
      const int i = t + s * 256;
      const int row = i >> 5, cb = i & 31;
      gload_lds16(Kbase + (size_t)row * 2048 + kc + cb * 8, sK + i * 8);
    }
    __syncthreads();
#pragma unroll
    for (int u = 0; u < 7; ++u) {
      const int tl = w + u * 4;
      if (tl < 25) {
        const int qi = tl / 5, kj = tl % 5;
#pragma unroll
        for (int k0 = 0; k0 < 256; k0 += 32) {
          bf16x8 a = *(const bf16x8*)(sQ + (qi * 16 + (lane & 15)) * 256 + k0 + (lane >> 4) * 8);
          bf16x8 kk = *(const bf16x8*)(sK + (kj * 16 + (lane & 15)) * 256 + k0 + (lane >> 4) * 8);
          acc[u] = MFMA16(a, kk, acc[u]);
        }
      }
    }
    __syncthreads();
  }
  float* Sp = Spart + (size_t)(b * 4 + kq) * 6400;
#pragma unroll
  for (int u = 0; u < 7; ++u) {
    const int tl = w + u * 4;
    if (tl < 25) {
      const int qi = tl / 5, kj = tl % 5;
#pragma unroll
      for (int jj = 0; jj < 4; ++jj) {
        const int r = qi * 16 + (lane >> 4) * 4 + jj;
        const int c = kj * 16 + (lane & 15);
        Sp[r * 80 + c] = acc[u][jj];
      }
    }
  }
}

// ---------------------------------------------------------------- attention 2/3: softmax
__global__ __launch_bounds__(256)
void attn_soft(const float* __restrict__ Spart, const float* __restrict__ mask,
               __bf16* __restrict__ Pg) {
  __shared__ float S[80 * 81];
  const int b = blockIdx.x, t = threadIdx.x;
  const float* Sp = Spart + (size_t)b * 4 * 6400;
  for (int idx = t; idx < 6400; idx += 256) {
    const int r = idx / 80, c = idx - r * 80;
    S[r * 81 + c] = Sp[idx] + Sp[6400 + idx] + Sp[12800 + idx] + Sp[19200 + idx];
  }
  __syncthreads();
  if (t < 80) {
    const float scale = 0.02209708691207961f;  // 1/sqrt(2048)
    float mx = -1e30f;
    for (int k = 0; k < 80; ++k) {
      float v = S[t * 81 + k] * scale * mask[t * 80 + k];
      S[t * 81 + k] = v;
      mx = fmaxf(mx, v);
    }
    float sum = 0.f;
    for (int k = 0; k < 80; ++k) {
      float e = __expf(S[t * 81 + k] - mx);
      S[t * 81 + k] = e;
      sum += e;
    }
    const float r = 1.f / sum;
    __bf16* Pr = Pg + (size_t)b * 7680 + t * 96;
    for (int k = 0; k < 80; ++k) Pr[k] = (__bf16)(S[t * 81 + k] * r);
    for (int k = 80; k < 96; ++k) Pr[k] = (__bf16)0.f;
  }
}

// ---------------------------------------------------------------- attention 3/3: PV + epilogue
__global__ __launch_bounds__(256)
void attn_pv(const __bf16* __restrict__ Pg, const float* __restrict__ feats,
             const float* __restrict__ adj, float* __restrict__ out) {
  __shared__ __bf16 Ft[64 * 104];
  const int b = blockIdx.x >> 2, hq = blockIdx.x & 3;
  const int hb = hq * 49;
  const int t = threadIdx.x, lane = t & 63, w = t >> 6;
  for (int idx = t; idx < 4704; idx += 256) {  // 96*49
    const int k = idx / 49, h = idx - k * 49;
    Ft[h * 104 + k] = (k < 80) ? (__bf16)feats[(size_t)b * 15680 + k * 196 + hb + h]
                               : (__bf16)0.f;
  }
  __syncthreads();
  const __bf16* Pb = Pg + (size_t)b * 7680;
#pragma unroll
  for (int u = 0; u < 5; ++u) {
    const int tl = w + u * 4;  // 0..19
    const int ci = tl >> 2, hj = tl & 3;
    f32x4 a2 = (f32x4){0.f, 0.f, 0.f, 0.f};
#pragma unroll
    for (int k0 = 0; k0 < 96; k0 += 32) {
      bf16x8 pa = *(const bf16x8*)(Pb + (ci * 16 + (lane & 15)) * 96 + k0 + (lane >> 4) * 8);
      bf16x8 fb = *(const bf16x8*)(Ft + (hj * 16 + (lane & 15)) * 104 + k0 + (lane >> 4) * 8);
      a2 = MFMA16(pa, fb, a2);
    }
#pragma unroll
    for (int jj = 0; jj < 4; ++jj) {
      const int c = ci * 16 + (lane >> 4) * 4 + jj;
      const int h2 = hj * 16 + (lane & 15);
      if (h2 < 49) {
        const size_t o = (size_t)b * 15680 + (size_t)c * 196 + hb + h2;
        out[o] = (feats[o] + a2[jj]) * adj[o];
      }
    }
  }
}

// ---------------------------------------------------------------- launch
extern "C" void kernel_launch(void* const* d_in, const int* in_sizes, int n_in,
                              void* d_out, int out_size, void* d_ws, size_t ws_size,
                              hipStream_t stream) {
  const float* features = (const float*)d_in[0];
  const float* sem      = (const float*)d_in[1];
  const float* mask     = (const float*)d_in[2];
  const float* Wq_w     = (const float*)d_in[3];
  const float* Wq_b     = (const float*)d_in[4];
  const float* Wk_w     = (const float*)d_in[5];
  const float* Wk_b     = (const float*)d_in[6];
  const float* Wa_w     = (const float*)d_in[7];
  const float* Wa_b     = (const float*)d_in[8];
  float* out = (float*)d_out;

  char* ws = (char*)d_ws;
  __bf16* semb = (__bf16*)ws;                   // 5120x2048 bf16
  __bf16* wcat = (__bf16*)(ws + 20971520);      // 4292x2048 bf16
  __bf16* Qb   = (__bf16*)(ws + 38551552);
  __bf16* Kb   = (__bf16*)(ws + 59523072);
  float*  adj  = (float*)(ws + 80494592);       // 5120x196 f32 (total 84.5 MB)
  float*  Spart = (float*)ws;                   // aliases semb (dead after gemm)
  __bf16* Pg    = (__bf16*)(ws + 20971520);     // aliases wcat (dead after gemm)

  cvt_all<<<9412, 256, 0, stream>>>(sem, Wq_w, Wk_w, Wa_w, semb, wcat);
  gemm_fused<<<459, 512, 0, stream>>>(semb, wcat, Wq_b, Wk_b, Wa_b, Qb, Kb, adj);
  attn_s<<<256, 256, 0, stream>>>(Qb, Kb, Spart);
  attn_soft<<<64, 256, 0, stream>>>(Spart, mask, Pg);
  attn_pv<<<256, 256, 0, stream>>>(Pg, features, adj, out);
}

// Round 6
// 158.419 us; speedup vs baseline: 2.0559x; 1.0099x over previous
//
#include <hip/hip_runtime.h>

typedef __bf16 bf16x8 __attribute__((ext_vector_type(8)));
typedef float f32x4 __attribute__((ext_vector_type(4)));

#define AS1 __attribute__((address_space(1)))
#define AS3 __attribute__((address_space(3)))

__device__ __forceinline__ void gload_lds16(const void* g, void* l) {
  __builtin_amdgcn_global_load_lds((const AS1 void*)g, (AS3 void*)l, 16, 0, 0);
}

#define MFMA16(a, b, c) __builtin_amdgcn_mfma_f32_16x16x32_bf16((a), (b), (c), 0, 0, 0)

// ---------------------------------------------------------------- fp32 -> bf16 (all 4 tensors, one dispatch)
__global__ __launch_bounds__(256)
void cvt_all(const float* __restrict__ sem, const float* __restrict__ wq,
             const float* __restrict__ wk, const float* __restrict__ wa,
             __bf16* __restrict__ semb, __bf16* __restrict__ wcat) {
  int i = blockIdx.x * 256 + threadIdx.x;
  if (i >= 2409472) return;
  const float* in;
  __bf16* out;
  int j;
  if (i < 1310720) { in = sem; out = semb; j = i; }
  else if (i < 1835008) { in = wq; out = wcat; j = i - 1310720; }
  else if (i < 2359296) { in = wk; out = wcat + 4194304; j = i - 1835008; }
  else { in = wa; out = wcat + 8388608; j = i - 2359296; }
  const float4* p = (const float4*)in;
  float4 a = p[2 * j], b = p[2 * j + 1];
  bf16x8 v;
  v[0] = (__bf16)a.x; v[1] = (__bf16)a.y; v[2] = (__bf16)a.z; v[3] = (__bf16)a.w;
  v[4] = (__bf16)b.x; v[5] = (__bf16)b.y; v[6] = (__bf16)b.z; v[7] = (__bf16)b.w;
  *(bf16x8*)(out + (size_t)j * 8) = v;
}

// ---------------------------------------------------------------- fused projection GEMM, 192x128 tiles
// C[5184(pad),4352] = semb[5120,2048] @ Wcat[4292,2048]^T.
// cols [0,2048)->Qb bf16 +qb; [2048,4096)->Kb bf16 +kb; [4096,4292)->adj sigmoid.
// 512 thr = 8 waves (4M x 2N), wave tile 48x64. BK=64, 32 iters.
// LDS = 80 KiB exactly (A dbuf 2x24 KiB + B dbuf 2x16 KiB) -> 2 blocks/CU, 4 waves/SIMD:
// cross-block overlap hides staging latency (m97/m114 mechanism); one vmcnt(0)+barrier per iter.
__global__ __launch_bounds__(512, 4)
void gemm_fused(const __bf16* __restrict__ A, const __bf16* __restrict__ B,
                const float* __restrict__ qbias, const float* __restrict__ kbias,
                const float* __restrict__ abias, __bf16* __restrict__ Qo,
                __bf16* __restrict__ Ko, float* __restrict__ adj) {
  __shared__ char smem[81920];
  char* smc = smem;
  // bijective XCD chunking (nwg=918, q=114, r=6) + 8-wide tn-band, tm-major in band
  const int bid = blockIdx.x;
  const int xcd = bid & 7, sidx = bid >> 3;
  const int wgid = (xcd < 6 ? xcd * 115 : 690 + (xcd - 6) * 114) + sidx;
  int tm, tn;
  if (wgid < 864) {
    const int band = wgid / 216, rem = wgid % 216;
    tm = rem >> 3;
    tn = band * 8 + (rem & 7);
  } else {
    const int rem = wgid - 864;
    tm = rem >> 1;
    tn = 32 + (rem & 1);
  }

  const int t = threadIdx.x;
  const int lane = t & 63;
  const int w = t >> 6, wm = w >> 1, wn = w & 1;

  // staging constants (linear LDS dest; swizzle folded into global source column)
  const int r0 = t >> 3;                       // 0..63
  const int colx = ((t & 7) ^ (r0 & 7)) * 8;   // pre-swizzled source column (elements)
  const int t16 = t * 16;

#define STAGE_A(kk, pb) do {                                                 \
    char* dstA = smc + (pb) * 24576 + t16;                                   \
    int gr0 = tm * 192 + r0;        gr0 = gr0 < 5120 ? gr0 : 5119;           \
    int gr1 = tm * 192 + 64 + r0;   gr1 = gr1 < 5120 ? gr1 : 5119;           \
    int gr2 = tm * 192 + 128 + r0;  gr2 = gr2 < 5120 ? gr2 : 5119;           \
    gload_lds16(A + (size_t)gr0 * 2048 + (kk) * 64 + colx, dstA);            \
    gload_lds16(A + (size_t)gr1 * 2048 + (kk) * 64 + colx, dstA + 8192);     \
    gload_lds16(A + (size_t)gr2 * 2048 + (kk) * 64 + colx, dstA + 16384);    \
  } while (0)

#define STAGE_B(kk, pb) do {                                                 \
    char* dstB = smc + 49152 + (pb) * 16384 + t16;                           \
    int gr0 = tn * 128 + r0;        gr0 = gr0 < 4292 ? gr0 : 4291;           \
    int gr1 = tn * 128 + 64 + r0;   gr1 = gr1 < 4292 ? gr1 : 4291;           \
    gload_lds16(B + (size_t)gr0 * 2048 + (kk) * 64 + colx, dstB);            \
    gload_lds16(B + (size_t)gr1 * 2048 + (kk) * 64 + colx, dstB + 8192);     \
  } while (0)

  // fragment-read constants (swizzled ds_read)
  const int rbase = (lane & 15) * 128;
  const int g16 = (lane >> 4) * 16;
  const int x16 = (lane & 7) << 4;
  const int aoff = wm * 6144 + rbase;   // wm*48 rows * 128B
  const int boff = wn * 8192 + rbase;   // wn*64 rows * 128B

#define LDA(ab, m, kh) (*(const bf16x8*)((ab) + aoff + (m) * 2048 + ((((kh) * 64) + g16) ^ x16)))
#define LDB(bb, n, kh) (*(const bf16x8*)((bb) + boff + (n) * 2048 + ((((kh) * 64) + g16) ^ x16)))

  f32x4 acc[3][4];
#pragma unroll
  for (int m = 0; m < 3; ++m)
#pragma unroll
    for (int n = 0; n < 4; ++n) acc[m][n] = (f32x4){0.f, 0.f, 0.f, 0.f};

  // prologue: tile 0
  STAGE_A(0, 0); STAGE_B(0, 0);
  asm volatile("s_waitcnt vmcnt(0)" ::: "memory");
  __builtin_amdgcn_s_barrier();

  for (int j = 0; j < 32; ++j) {
    char* Ab = smc + (j & 1) * 24576;
    char* Bb = smc + 49152 + (j & 1) * 16384;
    bf16x8 af[3][2], bf[2][2], bg[2][2];
    // frags for cluster 1
#pragma unroll
    for (int m = 0; m < 3; ++m) { af[m][0] = LDA(Ab, m, 0); af[m][1] = LDA(Ab, m, 1); }
#pragma unroll
    for (int n = 0; n < 2; ++n) { bf[n][0] = LDB(Bb, n, 0); bf[n][1] = LDB(Bb, n, 1); }
    // stage next tile into other buffer
    if (j < 31) { STAGE_A(j + 1, (j + 1) & 1); STAGE_B(j + 1, (j + 1) & 1); }
    __builtin_amdgcn_s_setprio(1);
#pragma unroll
    for (int m = 0; m < 3; ++m)
#pragma unroll
      for (int n = 0; n < 2; ++n) {
        acc[m][n] = MFMA16(af[m][0], bf[n][0], acc[m][n]);
        acc[m][n] = MFMA16(af[m][1], bf[n][1], acc[m][n]);
      }
    __builtin_amdgcn_s_setprio(0);
    // frags + cluster 2
#pragma unroll
    for (int n = 0; n < 2; ++n) { bg[n][0] = LDB(Bb, n + 2, 0); bg[n][1] = LDB(Bb, n + 2, 1); }
    __builtin_amdgcn_s_setprio(1);
#pragma unroll
    for (int m = 0; m < 3; ++m)
#pragma unroll
      for (int n = 0; n < 2; ++n) {
        acc[m][n + 2] = MFMA16(af[m][0], bg[n][0], acc[m][n + 2]);
        acc[m][n + 2] = MFMA16(af[m][1], bg[n][1], acc[m][n + 2]);
      }
    __builtin_amdgcn_s_setprio(0);
    if (j < 31) asm volatile("s_waitcnt vmcnt(0)" ::: "memory");
    __builtin_amdgcn_s_barrier();
  }

  // ---- epilogue
  if (tn < 32) {
    // bias-add + bf16 into LDS [192][136], then coalesced 16B row-major stores
    __bf16* so = (__bf16*)smc;
    const float* bias = (tn < 16) ? (qbias + tn * 128) : (kbias + (tn - 16) * 128);
#pragma unroll
    for (int n = 0; n < 4; ++n) {
      const int colb = wn * 64 + n * 16 + (lane & 15);
      const float bv = bias[colb];
#pragma unroll
      for (int m = 0; m < 3; ++m) {
        const int rw = wm * 48 + m * 16 + (lane >> 4) * 4;
#pragma unroll
        for (int jj = 0; jj < 4; ++jj)
          so[(rw + jj) * 136 + colb] = (__bf16)(acc[m][n][jj] + bv);
      }
    }
    __syncthreads();
    __bf16* dst = (tn < 16) ? (Qo + tn * 128) : (Ko + (tn - 16) * 128);
    for (int idx = t; idx < 3072; idx += 512) {  // 192 rows x 16 16B-chunks
      const int row = idx >> 4, c = idx & 15;
      const int grow = tm * 192 + row;
      if (grow < 5120) {
        bf16x8 v = *(const bf16x8*)(so + row * 136 + c * 8);
        *(bf16x8*)(dst + (size_t)grow * 2048 + c * 8) = v;
      }
    }
  } else {
    // adj region: scattered f32 sigmoid stores (small)
#pragma unroll
    for (int n = 0; n < 4; ++n) {
      const int colg = (tn - 32) * 128 + wn * 64 + n * 16 + (lane & 15);
      if (colg < 196) {
        const float bv = abias[colg];
#pragma unroll
        for (int m = 0; m < 3; ++m)
#pragma unroll
          for (int jj = 0; jj < 4; ++jj) {
            const int row = tm * 192 + wm * 48 + m * 16 + (lane >> 4) * 4 + jj;
            if (row < 5120) {
              const float v = acc[m][n][jj] + bv;
              adj[(size_t)row * 196 + colg] = 1.f / (1.f + __expf(-v));
            }
          }
      }
    }
  }
#undef STAGE_A
#undef STAGE_B
#undef LDA
#undef LDB
}

// ---------------------------------------------------------------- attention 1/3: partial S
__global__ __launch_bounds__(256)
void attn_s(const __bf16* __restrict__ Qb, const __bf16* __restrict__ Kb,
            float* __restrict__ Spart) {
  __shared__ char smem[81920];
  __bf16* sQ = (__bf16*)smem;            // [80][256]
  __bf16* sK = (__bf16*)(smem + 40960);  // [80][256]
  const int b = blockIdx.x >> 2, kq = blockIdx.x & 3;
  const int t = threadIdx.x, lane = t & 63, w = t >> 6;
  const __bf16* Qbase = Qb + (size_t)b * 163840;
  const __bf16* Kbase = Kb + (size_t)b * 163840;

  f32x4 acc[7];
#pragma unroll
  for (int u = 0; u < 7; ++u) acc[u] = (f32x4){0.f, 0.f, 0.f, 0.f};

  for (int kc = kq * 512; kc < kq * 512 + 512; kc += 256) {
#pragma unroll
    for (int s = 0; s < 10; ++s) {
      const int i = t + s * 256;
      const int row = i >> 5, cb = i & 31;
      gload_lds16(Qbase + (size_t)row * 2048 + kc + cb * 8, sQ + i * 8);
    }
#pragma unroll
    for (int s = 0; s < 10; ++s) {
      const int i = t + s * 256;
      const int row = i >> 5, cb = i & 31;
      gload_lds16(Kbase + (size_t)row * 2048 + kc + cb * 8, sK + i * 8);
    }
    __syncthreads();
#pragma unroll
    for (int u = 0; u < 7; ++u) {
      const int tl = w + u * 4;
      if (tl < 25) {
        const int qi = tl / 5, kj = tl % 5;
#pragma unroll
        for (int k0 = 0; k0 < 256; k0 += 32) {
          bf16x8 a = *(const bf16x8*)(sQ + (qi * 16 + (lane & 15)) * 256 + k0 + (lane >> 4) * 8);
          bf16x8 kk = *(const bf16x8*)(sK + (kj * 16 + (lane & 15)) * 256 + k0 + (lane >> 4) * 8);
          acc[u] = MFMA16(a, kk, acc[u]);
        }
      }
    }
    __syncthreads();
  }
  float* Sp = Spart + (size_t)(b * 4 + kq) * 6400;
#pragma unroll
  for (int u = 0; u < 7; ++u) {
    const int tl = w + u * 4;
    if (tl < 25) {
      const int qi = tl / 5, kj = tl % 5;
#pragma unroll
      for (int jj = 0; jj < 4; ++jj) {
        const int r = qi * 16 + (lane >> 4) * 4 + jj;
        const int c = kj * 16 + (lane & 15);
        Sp[r * 80 + c] = acc[u][jj];
      }
    }
  }
}

// ---------------------------------------------------------------- attention 2/3: softmax
__global__ __launch_bounds__(256)
void attn_soft(const float* __restrict__ Spart, const float* __restrict__ mask,
               __bf16* __restrict__ Pg) {
  __shared__ float S[80 * 81];
  const int b = blockIdx.x, t = threadIdx.x;
  const float* Sp = Spart + (size_t)b * 4 * 6400;
  for (int idx = t; idx < 6400; idx += 256) {
    const int r = idx / 80, c = idx - r * 80;
    S[r * 81 + c] = Sp[idx] + Sp[6400 + idx] + Sp[12800 + idx] + Sp[19200 + idx];
  }
  __syncthreads();
  if (t < 80) {
    const float scale = 0.02209708691207961f;  // 1/sqrt(2048)
    float mx = -1e30f;
    for (int k = 0; k < 80; ++k) {
      float v = S[t * 81 + k] * scale * mask[t * 80 + k];
      S[t * 81 + k] = v;
      mx = fmaxf(mx, v);
    }
    float sum = 0.f;
    for (int k = 0; k < 80; ++k) {
      float e = __expf(S[t * 81 + k] - mx);
      S[t * 81 + k] = e;
      sum += e;
    }
    const float r = 1.f / sum;
    __bf16* Pr = Pg + (size_t)b * 7680 + t * 96;
    for (int k = 0; k < 80; ++k) Pr[k] = (__bf16)(S[t * 81 + k] * r);
    for (int k = 80; k < 96; ++k) Pr[k] = (__bf16)0.f;
  }
}

// ---------------------------------------------------------------- attention 3/3: PV + epilogue
__global__ __launch_bounds__(256)
void attn_pv(const __bf16* __restrict__ Pg, const float* __restrict__ feats,
             const float* __restrict__ adj, float* __restrict__ out) {
  __shared__ __bf16 Ft[64 * 104];
  const int b = blockIdx.x >> 2, hq = blockIdx.x & 3;
  const int hb = hq * 49;
  const int t = threadIdx.x, lane = t & 63, w = t >> 6;
  for (int idx = t; idx < 4704; idx += 256) {  // 96*49
    const int k = idx / 49, h = idx - k * 49;
    Ft[h * 104 + k] = (k < 80) ? (__bf16)feats[(size_t)b * 15680 + k * 196 + hb + h]
                               : (__bf16)0.f;
  }
  __syncthreads();
  const __bf16* Pb = Pg + (size_t)b * 7680;
#pragma unroll
  for (int u = 0; u < 5; ++u) {
    const int tl = w + u * 4;  // 0..19
    const int ci = tl >> 2, hj = tl & 3;
    f32x4 a2 = (f32x4){0.f, 0.f, 0.f, 0.f};
#pragma unroll
    for (int k0 = 0; k0 < 96; k0 += 32) {
      bf16x8 pa = *(const bf16x8*)(Pb + (ci * 16 + (lane & 15)) * 96 + k0 + (lane >> 4) * 8);
      bf16x8 fb = *(const bf16x8*)(Ft + (hj * 16 + (lane & 15)) * 104 + k0 + (lane >> 4) * 8);
      a2 = MFMA16(pa, fb, a2);
    }
#pragma unroll
    for (int jj = 0; jj < 4; ++jj) {
      const int c = ci * 16 + (lane >> 4) * 4 + jj;
      const int h2 = hj * 16 + (lane & 15);
      if (h2 < 49) {
        const size_t o = (size_t)b * 15680 + (size_t)c * 196 + hb + h2;
        out[o] = (feats[o] + a2[jj]) * adj[o];
      }
    }
  }
}

// ---------------------------------------------------------------- launch
extern "C" void kernel_launch(void* const* d_in, const int* in_sizes, int n_in,
                              void* d_out, int out_size, void* d_ws, size_t ws_size,
                              hipStream_t stream) {
  const float* features = (const float*)d_in[0];
  const float* sem      = (const float*)d_in[1];
  const float* mask     = (const float*)d_in[2];
  const float* Wq_w     = (const float*)d_in[3];
  const float* Wq_b     = (const float*)d_in[4];
  const float* Wk_w     = (const float*)d_in[5];
  const float* Wk_b     = (const float*)d_in[6];
  const float* Wa_w     = (const float*)d_in[7];
  const float* Wa_b     = (const float*)d_in[8];
  float* out = (float*)d_out;

  char* ws = (char*)d_ws;
  __bf16* semb = (__bf16*)ws;                   // 5120x2048 bf16
  __bf16* wcat = (__bf16*)(ws + 20971520);      // 4292x2048 bf16
  __bf16* Qb   = (__bf16*)(ws + 38551552);
  __bf16* Kb   = (__bf16*)(ws + 59523072);
  float*  adj  = (float*)(ws + 80494592);       // 5120x196 f32 (total 84.5 MB)
  float*  Spart = (float*)ws;                   // aliases semb (dead after gemm)
  __bf16* Pg    = (__bf16*)(ws + 20971520);     // aliases wcat (dead after gemm)

  cvt_all<<<9412, 256, 0, stream>>>(sem, Wq_w, Wk_w, Wa_w, semb, wcat);
  gemm_fused<<<918, 512, 0, stream>>>(semb, wcat, Wq_b, Wk_b, Wa_b, Qb, Kb, adj);
  attn_s<<<256, 256, 0, stream>>>(Qb, Kb, Spart);
  attn_soft<<<64, 256, 0, stream>>>(Spart, mask, Pg);
  attn_pv<<<256, 256, 0, stream>>>(Pg, features, adj, out);
}